// Round 20
// baseline (142.694 us; speedup 1.0000x reference)
//
#include <hip/hip_runtime.h>
#include <hip/hip_bf16.h>

#define B_   2
#define T_   2048
#define HID_ 1024
#define NH_  16
#define HD_  64
#define K_   1024
#define M_   (B_*T_)

typedef __attribute__((ext_vector_type(8)))  short bf16x8;
typedef __attribute__((ext_vector_type(4)))  float f32x4;
typedef __attribute__((ext_vector_type(16))) float f32x16;
typedef __attribute__((ext_vector_type(4)))  unsigned int u32x4;
typedef __attribute__((ext_vector_type(2)))  unsigned int u32x2;

#define LOG2E 1.44269504088896340736f

__device__ inline unsigned short f2bf(float f) {
    __hip_bfloat16 h = __float2bfloat16(f);
    return __builtin_bit_cast(unsigned short, h);
}
__device__ inline unsigned int pk2(float a, float b) {
    return (unsigned int)f2bf(a) | ((unsigned int)f2bf(b) << 16);
}
// truncation pack: (a>>16) | (b & 0xffff0000) in ONE v_perm_b32
__device__ inline unsigned int pkt(float a, float b) {
    return __builtin_amdgcn_perm(__builtin_bit_cast(unsigned, a),
                                 __builtin_bit_cast(unsigned, b), 0x03020706u);
}
__device__ inline bf16x8 cvt8(float4 a, float4 b) {
    bf16x8 r;
    r[0]=(short)f2bf(a.x); r[1]=(short)f2bf(a.y); r[2]=(short)f2bf(a.z); r[3]=(short)f2bf(a.w);
    r[4]=(short)f2bf(b.x); r[5]=(short)f2bf(b.y); r[6]=(short)f2bf(b.z); r[7]=(short)f2bf(b.w);
    return r;
}
// async global->LDS, 16 bytes/lane. LDS dest is wave-uniform base; HW adds lane*16.
__device__ inline void gll16(const void* g, void* l) {
    __builtin_amdgcn_global_load_lds(
        (const __attribute__((address_space(1))) unsigned int*)g,
        (__attribute__((address_space(3))) unsigned int*)l, 16, 0, 0);
}

// ---------------- fp32 -> bf16 cast, single launch (x + 4 weights) ----------------
__global__ __launch_bounds__(256)
void cast_all(const float* __restrict__ x,
              const float* __restrict__ W0, const float* __restrict__ W1,
              const float* __restrict__ W2, const float* __restrict__ W3,
              unsigned short* __restrict__ xo,
              unsigned short* __restrict__ o0, unsigned short* __restrict__ o1,
              unsigned short* __restrict__ o2, unsigned short* __restrict__ o3) {
    const int blk = blockIdx.x;
    const float* in;
    unsigned short* out;
    int i;
    if (blk < 2048) {
        in = x; out = xo; i = blk * 256 + threadIdx.x;
    } else {
        const int wb = blk - 2048, sec = wb >> 9;
        in  = (sec == 0) ? W0 : (sec == 1) ? W1 : (sec == 2) ? W2 : W3;
        out = (sec == 0) ? o0 : (sec == 1) ? o1 : (sec == 2) ? o2 : o3;
        i = (wb & 511) * 256 + threadIdx.x;
    }
    float4 a = ((const float4*)in)[2*i], b = ((const float4*)in)[2*i + 1];
    ((bf16x8*)out)[i] = cvt8(a, b);
}

// ---------------- bf16 GEMM-NT: global_load_lds T3 2-phase double-buffer ----------------
// Double-buffered linear LDS [2][128][64] per operand (64 KB). Per K-step:
// issue STAGE(buf^1, k+64) FIRST, then ds_read+MFMA from buf, then ONE barrier
// (compiler's vmcnt(0) drain happens after the loads had the whole MFMA phase).
// Index mappings correctness-proven in R11. Epilogues unchanged (RoPE/kappa-V/fp32).
template<int TYPE>
__global__ __launch_bounds__(256)
void gemm_k(const unsigned short* __restrict__ A, const unsigned short* __restrict__ W0,
            const unsigned short* __restrict__ W1, const unsigned short* __restrict__ W2,
            const float* __restrict__ cs, const float* __restrict__ sn,
            unsigned short* __restrict__ qb, unsigned short* __restrict__ kb,
            unsigned short* __restrict__ vtb, float* __restrict__ fout) {
    __shared__ unsigned short As[2][128*64];
    __shared__ unsigned short Bs[2][128*64];
    const int tid = threadIdx.x;
    const int w = tid >> 6, lane = tid & 63;
    const int u = lane >> 4, c = lane & 15;
    const int bid = blockIdx.x;
    const int xcd = bid & 7, idx = bid >> 3;
    int bmi, bni;
    if constexpr (TYPE == 0) {          // 32 x 24 tiles, 8 XCD x (8bm x 12bn)
        bmi = (xcd & 3) * 8 + (idx & 7);
        bni = (xcd >> 2) * 12 + (idx >> 3);
    } else {                            // 32 x 8 tiles, 8 XCD x (8bm x 4bn)
        bmi = (xcd & 3) * 8 + (idx & 7);
        bni = (xcd >> 2) * 4 + (idx >> 3);
    }
    const int bm = bmi * 128, bn = bni * 128;
    const int wm = (w & 1) * 64, wn = (w >> 1) * 64;

    const unsigned short* Wsec;
    int wrowbase;
    if constexpr (TYPE == 0) {
        const int sec = bn >> 10;
        Wsec = (sec == 0) ? W0 : ((sec == 1) ? W1 : W2);
        wrowbase = bn & 1023;
    } else {
        Wsec = W0;
        wrowbase = bn;
    }
    const unsigned short* Ab = A + (size_t)bm * K_;
    const unsigned short* Wb = Wsec + (size_t)wrowbase * K_;
    const int srow = lane >> 3;            // 0..7 within 8-row segment
    const int scol = (lane & 7) * 8;       // elem col within 64

    f32x4 acc[4][4] = {};

    auto stage = [&](int buf, int k0) {
        #pragma unroll
        for (int s4 = 0; s4 < 4; ++s4) {
            const int seg = w * 4 + s4;    // 16 segments of 8 rows
            gll16(Ab + (size_t)(seg * 8 + srow) * K_ + k0 + scol,
                  (char*)&As[buf][0] + seg * 1024);
            gll16(Wb + (size_t)(seg * 8 + srow) * K_ + k0 + scol,
                  (char*)&Bs[buf][0] + seg * 1024);
        }
    };

    // prologue: stage tile 0 into buf 0, drain, enter steady state
    stage(0, 0);
    __syncthreads();
    int cur = 0;
    for (int k0 = 0; k0 < K_; k0 += 64) {
        if (k0 + 64 < K_) stage(cur ^ 1, k0 + 64);   // issue next tile FIRST
        #pragma unroll
        for (int kk = 0; kk < 2; ++kk) {
            bf16x8 af[4], bfr[4];
            #pragma unroll
            for (int mi = 0; mi < 4; ++mi)
                af[mi] = *(const bf16x8*)&As[cur][(wm + mi*16 + c) * 64 + kk*32 + u*8];
            #pragma unroll
            for (int ni = 0; ni < 4; ++ni)
                bfr[ni] = *(const bf16x8*)&Bs[cur][(wn + ni*16 + c) * 64 + kk*32 + u*8];
            #pragma unroll
            for (int mi = 0; mi < 4; ++mi)
                #pragma unroll
                for (int ni = 0; ni < 4; ++ni)
                    acc[mi][ni] = __builtin_amdgcn_mfma_f32_16x16x32_bf16(
                        af[mi], bfr[ni], acc[mi][ni], 0, 0, 0);
        }
        __syncthreads();                   // drains next-tile loads + orders reads
        cur ^= 1;
    }

    if constexpr (TYPE == 1) {
        #pragma unroll
        for (int mi = 0; mi < 4; ++mi)
            #pragma unroll
            for (int ni = 0; ni < 4; ++ni)
                #pragma unroll
                for (int r = 0; r < 4; ++r)
                    fout[(size_t)(bm + wm + 16*mi + 4*u + r) * HID_ + (bn + wn + 16*ni + c)] =
                        acc[mi][ni][r];
    } else {
        const int sec = bn >> 10;
        const int h = ((bn + wn) & 1023) >> 6;
        if (sec == 2) {
            #pragma unroll
            for (int mi = 0; mi < 4; ++mi)
                #pragma unroll
                for (int r = 0; r < 4; ++r) {
                    const int mg = bm + wm + 16*mi + 4*u + r;
                    const int bb = mg >> 11, t = mg & 2047;
                    const int tk = (t & ~12) | ((t & 4) << 1) | ((t & 8) >> 1);  // kappa
                    #pragma unroll
                    for (int ni = 0; ni < 4; ++ni)
                        vtb[((size_t)(bb*16 + h) * 64 + 16*ni + c) * 2048 + tk] =
                            f2bf(acc[mi][ni][r]);
                }
        } else {
            unsigned short* ob = sec ? kb : qb;
            const float qsc = sec ? 1.0f : (0.125f * LOG2E);   // q in log2 domain
            #pragma unroll
            for (int mi = 0; mi < 4; ++mi)
                #pragma unroll
                for (int r = 0; r < 4; ++r) {
                    const int mg = bm + wm + 16*mi + 4*u + r;
                    const int bb = mg >> 11, t = mg & 2047;
                    const size_t base = ((size_t)(bb*16 + h) * 2048 + t) * 64;
                    #pragma unroll
                    for (int ni = 0; ni < 2; ++ni) {
                        const int dlo = 16*ni + c;
                        const float cv = cs[t*64 + dlo], sv = sn[t*64 + dlo];
                        const float Aa = acc[mi][ni][r], Bb = acc[mi][ni+2][r];
                        ob[base + dlo]      = f2bf((Aa*cv - Bb*sv) * qsc);
                        ob[base + dlo + 32] = f2bf((Bb*cv + Aa*sv) * qsc);
                    }
                }
        }
    }
}

// ---------------- attn16 (unchanged from R18; best measured 61.5us) ----------------
__global__ __launch_bounds__(256)
void attn16(const unsigned short* __restrict__ q, const unsigned short* __restrict__ k,
            const unsigned short* __restrict__ vt, unsigned short* __restrict__ ab) {
    const int raw = blockIdx.x;                          // 1024 blocks
    const int bh     = (raw & 7) + 8 * ((raw >> 3) & 3); // same-bh -> same XCD
    const int qchunk = 31 - (raw >> 5);                  // heavy blocks first
    const int tid = threadIdx.x;
    const int wid = tid >> 6, lane = tid & 63;
    const int h = lane >> 5, c = lane & 31;
    const int b = bh >> 4, hh = bh & 15;
    const int q0 = qchunk * 64;
    const int qgcA = q0 + c, qgcB = q0 + 32 + c;
    const int stAd = 2 * qchunk;                         // tile A diag subtile
    const int NT   = 2 * qchunk + 2;                     // KV subtiles (tile B diag = NT-1)
    const unsigned short* qp = q  + (size_t)bh * (T_*64);
    const unsigned short* kp = k  + (size_t)bh * (T_*64);
    const unsigned short* vp = vt + (size_t)bh * (64*T_);

    const int kloff  = c * 64 + 8 * h;
    const int vloff0 = c * 2048 + 8 * h;
    const int vloff1 = vloff0 + 32 * 2048;

    bf16x8 qfA[4], qfB[4];
    {
        const unsigned short* qrowA = qp + (q0 + c) * 64 + 8 * h;
        const unsigned short* qrowB = qrowA + 32 * 64;
        #pragma unroll
        for (int s = 0; s < 4; ++s) {
            qfA[s] = *(const bf16x8*)(qrowA + s * 16);
            qfB[s] = *(const bf16x8*)(qrowB + s * 16);
        }
    }

    f32x16 OA0 = {}, OA1 = {}, OB0 = {}, OB1 = {};
    float mA = -1e30f, lA = 0.f, mB = -1e30f, lB = 0.f;

    auto loadK = [&](bf16x8 (&kf)[4], int st) {
        const unsigned short* kst = kp + (st << 11);
        #pragma unroll
        for (int s = 0; s < 4; ++s)
            kf[s] = *(const bf16x8*)(kst + kloff + s * 16);
    };

    auto process = [&](bf16x8 (&kf)[4], int st) {
        const int kvs = st << 5;
        const unsigned short* vst = vp + (st << 5);
        bf16x8 vf0 = *(const bf16x8*)(vst + vloff0);
        bf16x8 vf1 = *(const bf16x8*)(vst + vloff0 + 16);
        bf16x8 vf2 = *(const bf16x8*)(vst + vloff1);
        bf16x8 vf3 = *(const bf16x8*)(vst + vloff1 + 16);
        const bool doA = (st <= stAd);                   // uniform
        float pA[16], pB[16];
        float mxA = -1e30f, mxB;
        if (doA) {
            __builtin_amdgcn_s_setprio(1);
            f32x16 sa = {};
            #pragma unroll
            for (int s = 0; s < 4; ++s)
                sa = __builtin_amdgcn_mfma_f32_32x32x16_bf16(kf[s], qfA[s], sa, 0, 0, 0);
            __builtin_amdgcn_s_setprio(0);
            #pragma unroll
            for (int r = 0; r < 16; ++r) pA[r] = sa[r];
            if (st == stAd) {
                #pragma unroll
                for (int r = 0; r < 16; ++r) {
                    const int kk = kvs + (r & 3) + 8 * (r >> 2) + 4 * h;
                    if (kk > qgcA) pA[r] = -1e30f;
                }
            }
            const float a0 = fmaxf(fmaxf(pA[0],  pA[1]),  pA[2]);
            const float a1 = fmaxf(fmaxf(pA[3],  pA[4]),  pA[5]);
            const float a2 = fmaxf(fmaxf(pA[6],  pA[7]),  pA[8]);
            const float a3 = fmaxf(fmaxf(pA[9],  pA[10]), pA[11]);
            const float a4 = fmaxf(fmaxf(pA[12], pA[13]), pA[14]);
            mxA = fmaxf(fmaxf(fmaxf(a0, a1), fmaxf(a2, a3)), fmaxf(a4, pA[15]));
        }
        {
            __builtin_amdgcn_s_setprio(1);
            f32x16 sa = {};
            #pragma unroll
            for (int s = 0; s < 4; ++s)
                sa = __builtin_amdgcn_mfma_f32_32x32x16_bf16(kf[s], qfB[s], sa, 0, 0, 0);
            __builtin_amdgcn_s_setprio(0);
            #pragma unroll
            for (int r = 0; r < 16; ++r) pB[r] = sa[r];
            if (st == NT - 1) {
                #pragma unroll
                for (int r = 0; r < 16; ++r) {
                    const int kk = kvs + (r & 3) + 8 * (r >> 2) + 4 * h;
                    if (kk > qgcB) pB[r] = -1e30f;
                }
            }
            const float a0 = fmaxf(fmaxf(pB[0],  pB[1]),  pB[2]);
            const float a1 = fmaxf(fmaxf(pB[3],  pB[4]),  pB[5]);
            const float a2 = fmaxf(fmaxf(pB[6],  pB[7]),  pB[8]);
            const float a3 = fmaxf(fmaxf(pB[9],  pB[10]), pB[11]);
            const float a4 = fmaxf(fmaxf(pB[12], pB[13]), pB[14]);
            mxB = fmaxf(fmaxf(fmaxf(a0, a1), fmaxf(a2, a3)), fmaxf(a4, pB[15]));
        }
        // kf's last read was the B QK^T — prefetch st+4 into the SAME buffer now;
        // the load is covered by the softmax+PV below (~600cy).
        if (st + 4 < NT) loadK(kf, st + 4);
        if (!__all(fmaxf(mxA - mA, mxB - mB) <= 8.0f)) {
            if (doA) {
                const float fx = fmaxf(mxA, __shfl_xor(mxA, 32));
                const float mn = fmaxf(mA, fx);
                const float f = __builtin_amdgcn_exp2f(mA - mn);
                mA = mn; lA *= f;
                #pragma unroll
                for (int r = 0; r < 16; ++r) { OA0[r] *= f; OA1[r] *= f; }
            }
            {
                const float fx = fmaxf(mxB, __shfl_xor(mxB, 32));
                const float mn = fmaxf(mB, fx);
                const float f = __builtin_amdgcn_exp2f(mB - mn);
                mB = mn; lB *= f;
                #pragma unroll
                for (int r = 0; r < 16; ++r) { OB0[r] *= f; OB1[r] *= f; }
            }
        }
        if (doA) {
            float ps = 0.f;
            #pragma unroll
            for (int r = 0; r < 16; ++r) {
                pA[r] = __builtin_amdgcn_exp2f(pA[r] - mA);
                ps += pA[r];
            }
            lA += ps;
            u32x4 B0w = { pkt(pA[0],  pA[1]),  pkt(pA[2],  pA[3]),
                          pkt(pA[4],  pA[5]),  pkt(pA[6],  pA[7])  };
            u32x4 B1w = { pkt(pA[8],  pA[9]),  pkt(pA[10], pA[11]),
                          pkt(pA[12], pA[13]), pkt(pA[14], pA[15]) };
            bf16x8 PB0 = __builtin_bit_cast(bf16x8, B0w);
            bf16x8 PB1 = __builtin_bit_cast(bf16x8, B1w);
            __builtin_amdgcn_s_setprio(1);
            OA0 = __builtin_amdgcn_mfma_f32_32x32x16_bf16(vf0, PB0, OA0, 0, 0, 0);
            OA0 = __builtin_amdgcn_mfma_f32_32x32x16_bf16(vf1, PB1, OA0, 0, 0, 0);
            OA1 = __builtin_amdgcn_mfma_f32_32x32x16_bf16(vf2, PB0, OA1, 0, 0, 0);
            OA1 = __builtin_amdgcn_mfma_f32_32x32x16_bf16(vf3, PB1, OA1, 0, 0, 0);
            __builtin_amdgcn_s_setprio(0);
        }
        {
            float ps = 0.f;
            #pragma unroll
            for (int r = 0; r < 16; ++r) {
                pB[r] = __builtin_amdgcn_exp2f(pB[r] - mB);
                ps += pB[r];
            }
            lB += ps;
            u32x4 B0w = { pkt(pB[0],  pB[1]),  pkt(pB[2],  pB[3]),
                          pkt(pB[4],  pB[5]),  pkt(pB[6],  pB[7])  };
            u32x4 B1w = { pkt(pB[8],  pB[9]),  pkt(pB[10], pB[11]),
                          pkt(pB[12], pB[13]), pkt(pB[14], pB[15]) };
            bf16x8 PB0 = __builtin_bit_cast(bf16x8, B0w);
            bf16x8 PB1 = __builtin_bit_cast(bf16x8, B1w);
            __builtin_amdgcn_s_setprio(1);
            OB0 = __builtin_amdgcn_mfma_f32_32x32x16_bf16(vf0, PB0, OB0, 0, 0, 0);
            OB0 = __builtin_amdgcn_mfma_f32_32x32x16_bf16(vf1, PB1, OB0, 0, 0, 0);
            OB1 = __builtin_amdgcn_mfma_f32_32x32x16_bf16(vf2, PB0, OB1, 0, 0, 0);
            OB1 = __builtin_amdgcn_mfma_f32_32x32x16_bf16(vf3, PB1, OB1, 0, 0, 0);
            __builtin_amdgcn_s_setprio(0);
        }
    };

    bf16x8 kf_[4];
    if (wid < NT) {
        loadK(kf_, wid);
        for (int st = wid; st < NT; st += 4)
            process(kf_, st);
    }
    lA += __shfl_xor(lA, 32);
    lB += __shfl_xor(lB, 32);

    // ---- merge the 4 wave-partials in LDS (bf16-packed, stride 34 u32) ----
    __shared__ unsigned OSu[4][64 * 34];
    __shared__ float mS[4][64], lS[4][64];
    if (h == 0) {
        mS[wid][c] = mA;      lS[wid][c] = lA;
        mS[wid][32 + c] = mB; lS[wid][32 + c] = lB;
    }
    {
        unsigned* os = &OSu[wid][0];
        const int rbA = c * 34 + 2 * h;
        const int rbB = (32 + c) * 34 + 2 * h;
        #pragma unroll
        for (int j = 0; j < 4; ++j) {
            os[rbA + 4*j]          = pk2(OA0[4*j],   OA0[4*j+1]);
            os[rbA + 4*j + 1]      = pk2(OA0[4*j+2], OA0[4*j+3]);
            os[rbA + 16 + 4*j]     = pk2(OA1[4*j],   OA1[4*j+1]);
            os[rbA + 16 + 4*j + 1] = pk2(OA1[4*j+2], OA1[4*j+3]);
            os[rbB + 4*j]          = pk2(OB0[4*j],   OB0[4*j+1]);
            os[rbB + 4*j + 1]      = pk2(OB0[4*j+2], OB0[4*j+3]);
            os[rbB + 16 + 4*j]     = pk2(OB1[4*j],   OB1[4*j+1]);
            os[rbB + 16 + 4*j + 1] = pk2(OB1[4*j+2], OB1[4*j+3]);
        }
    }
    __syncthreads();

    const int ql = tid & 63, ug = (tid >> 6) * 8;   // 8 u32 = 16 d per thread
    const float M = fmaxf(fmaxf(mS[0][ql], mS[1][ql]), fmaxf(mS[2][ql], mS[3][ql]));
    float acc[16] = {};
    float L = 0.f;
    #pragma unroll
    for (int w2 = 0; w2 < 4; ++w2) {
        const float sc = __builtin_amdgcn_exp2f(mS[w2][ql] - M);
        L += lS[w2][ql] * sc;
        u32x4 pa = *(u32x4*)&OSu[w2][ql * 34 + ug];
        u32x4 pb = *(u32x4*)&OSu[w2][ql * 34 + ug + 4];
        #pragma unroll
        for (int t = 0; t < 4; ++t) {
            acc[2*t]     += __builtin_bit_cast(float, pa[t] << 16) * sc;
            acc[2*t+1]   += __builtin_bit_cast(float, pa[t] & 0xffff0000u) * sc;
            acc[8+2*t]   += __builtin_bit_cast(float, pb[t] << 16) * sc;
            acc[8+2*t+1] += __builtin_bit_cast(float, pb[t] & 0xffff0000u) * sc;
        }
    }
    const float inv = 1.0f / L;
    uint4 ov0, ov1;
    ov0.x = pk2(acc[0]*inv,  acc[1]*inv);
    ov0.y = pk2(acc[2]*inv,  acc[3]*inv);
    ov0.z = pk2(acc[4]*inv,  acc[5]*inv);
    ov0.w = pk2(acc[6]*inv,  acc[7]*inv);
    ov1.x = pk2(acc[8]*inv,  acc[9]*inv);
    ov1.y = pk2(acc[10]*inv, acc[11]*inv);
    ov1.z = pk2(acc[12]*inv, acc[13]*inv);
    ov1.w = pk2(acc[14]*inv, acc[15]*inv);
    unsigned short* orow = ab + ((size_t)(b * T_) + q0 + ql) * HID_ + hh * 64 + ug * 2;
    *(uint4*)orow       = ov0;
    *(uint4*)(orow + 8) = ov1;
}

extern "C" void kernel_launch(void* const* d_in, const int* in_sizes, int n_in,
                              void* d_out, int out_size, void* d_ws, size_t ws_size,
                              hipStream_t stream) {
    const float* x  = (const float*)d_in[0];
    const float* Wq = (const float*)d_in[1];
    const float* Wk = (const float*)d_in[2];
    const float* Wv = (const float*)d_in[3];
    const float* Wo = (const float*)d_in[4];
    const float* cs = (const float*)d_in[5];
    const float* sn = (const float*)d_in[6];
    char* wsb = (char*)d_ws;
    unsigned short* xb  = (unsigned short*)(wsb);                  // 8 MB
    unsigned short* wqb = (unsigned short*)(wsb + (8u  << 20));    // 2 MB each
    unsigned short* wkb = (unsigned short*)(wsb + (10u << 20));
    unsigned short* wvb = (unsigned short*)(wsb + (12u << 20));
    unsigned short* wob = (unsigned short*)(wsb + (14u << 20));
    unsigned short* qb  = (unsigned short*)(wsb + (16u << 20));
    unsigned short* kb  = (unsigned short*)(wsb + (24u << 20));
    unsigned short* vtb = (unsigned short*)(wsb + (32u << 20));
    unsigned short* ab  = (unsigned short*)(wsb + (40u << 20));

    cast_all<<<4096, 256, 0, stream>>>(x, Wq, Wk, Wv, Wo, xb, wqb, wkb, wvb, wob);

    gemm_k<0><<<768, 256, 0, stream>>>(
        xb, wqb, wkb, wvb, cs, sn, qb, kb, vtb, nullptr);
    attn16<<<1024, 256, 0, stream>>>(qb, kb, vtb, ab);
    gemm_k<1><<<256, 256, 0, stream>>>(
        ab, wob, nullptr, nullptr, nullptr, nullptr,
        nullptr, nullptr, nullptr, (float*)d_out);
}

// Round 21
// 117.237 us; speedup vs baseline: 1.2171x; 1.2171x over previous
//
#include <hip/hip_runtime.h>
#include <hip/hip_bf16.h>

#define B_   2
#define T_   2048
#define HID_ 1024
#define NH_  16
#define HD_  64
#define K_   1024
#define M_   (B_*T_)

typedef __attribute__((ext_vector_type(8)))  short bf16x8;
typedef __attribute__((ext_vector_type(4)))  float f32x4;
typedef __attribute__((ext_vector_type(16))) float f32x16;
typedef __attribute__((ext_vector_type(4)))  unsigned int u32x4;
typedef __attribute__((ext_vector_type(2)))  unsigned int u32x2;

#define LOG2E 1.44269504088896340736f

__device__ inline unsigned short f2bf(float f) {
    __hip_bfloat16 h = __float2bfloat16(f);
    return __builtin_bit_cast(unsigned short, h);
}
__device__ inline unsigned int pk2(float a, float b) {
    return (unsigned int)f2bf(a) | ((unsigned int)f2bf(b) << 16);
}
// truncation pack: (a>>16) | (b & 0xffff0000) in ONE v_perm_b32
__device__ inline unsigned int pkt(float a, float b) {
    return __builtin_amdgcn_perm(__builtin_bit_cast(unsigned, a),
                                 __builtin_bit_cast(unsigned, b), 0x03020706u);
}
__device__ inline bf16x8 cvt8(float4 a, float4 b) {
    bf16x8 r;
    r[0]=(short)f2bf(a.x); r[1]=(short)f2bf(a.y); r[2]=(short)f2bf(a.z); r[3]=(short)f2bf(a.w);
    r[4]=(short)f2bf(b.x); r[5]=(short)f2bf(b.y); r[6]=(short)f2bf(b.z); r[7]=(short)f2bf(b.w);
    return r;
}

// ---------------- fp32 -> bf16 cast, single launch (x + 4 weights) ----------------
__global__ __launch_bounds__(256)
void cast_all(const float* __restrict__ x,
              const float* __restrict__ W0, const float* __restrict__ W1,
              const float* __restrict__ W2, const float* __restrict__ W3,
              unsigned short* __restrict__ xo,
              unsigned short* __restrict__ o0, unsigned short* __restrict__ o1,
              unsigned short* __restrict__ o2, unsigned short* __restrict__ o3) {
    const int blk = blockIdx.x;
    const float* in;
    unsigned short* out;
    int i;
    if (blk < 2048) {
        in = x; out = xo; i = blk * 256 + threadIdx.x;
    } else {
        const int wb = blk - 2048, sec = wb >> 9;
        in  = (sec == 0) ? W0 : (sec == 1) ? W1 : (sec == 2) ? W2 : W3;
        out = (sec == 0) ? o0 : (sec == 1) ? o1 : (sec == 2) ? o2 : o3;
        i = (wb & 511) * 256 + threadIdx.x;
    }
    float4 a = ((const float4*)in)[2*i], b = ((const float4*)in)[2*i + 1];
    ((bf16x8*)out)[i] = cvt8(a, b);
}

// ---------------- bf16 GEMM-NT: reg-staged + XOR-swizzled LDS (proven best) ----------
// R20 lesson: global_load_lds forces a linear LDS layout whose fragment ds_read is a
// 16-way bank conflict (9.4M conflicts measured); the XOR swizzle here needs the
// reg-staged path and is conflict-free. XCD supertile 1D grid (neutral, kept).
template<int TYPE>
__global__ __launch_bounds__(256)
void gemm_k(const unsigned short* __restrict__ A, const unsigned short* __restrict__ W0,
            const unsigned short* __restrict__ W1, const unsigned short* __restrict__ W2,
            const float* __restrict__ cs, const float* __restrict__ sn,
            unsigned short* __restrict__ qb, unsigned short* __restrict__ kb,
            unsigned short* __restrict__ vtb, float* __restrict__ fout) {
    __shared__ unsigned short As[128*64];
    __shared__ unsigned short Bs[128*64];
    const int tid = threadIdx.x;
    const int w = tid >> 6, lane = tid & 63;
    const int u = lane >> 4, c = lane & 15;
    const int bid = blockIdx.x;
    const int xcd = bid & 7, idx = bid >> 3;
    int bmi, bni;
    if constexpr (TYPE == 0) {          // 32 x 24 tiles, 8 XCD x (8bm x 12bn)
        bmi = (xcd & 3) * 8 + (idx & 7);
        bni = (xcd >> 2) * 12 + (idx >> 3);
    } else {                            // 32 x 8 tiles, 8 XCD x (8bm x 4bn)
        bmi = (xcd & 3) * 8 + (idx & 7);
        bni = (xcd >> 2) * 4 + (idx >> 3);
    }
    const int bm = bmi * 128, bn = bni * 128;
    const int wm = (w & 1) * 64, wn = (w >> 1) * 64;
    const int srow = tid >> 3, scol = (tid & 7) << 3;

    const unsigned short* Wsec;
    int wrowbase;
    if constexpr (TYPE == 0) {
        const int sec = bn >> 10;
        Wsec = (sec == 0) ? W0 : ((sec == 1) ? W1 : W2);
        wrowbase = bn & 1023;
    } else {
        Wsec = W0;
        wrowbase = bn;
    }
    const unsigned short* Wp = Wsec + (size_t)(wrowbase + srow) * K_ + scol;
    const unsigned short* Ap = A + (size_t)(bm + srow) * K_ + scol;

    f32x4 acc[4][4] = {};
    bf16x8 ra[4], rb[4];

    auto loadin = [&](int k0) {
        #pragma unroll
        for (int i = 0; i < 4; ++i) {
            ra[i] = *(const bf16x8*)(Ap + (size_t)i * 32 * K_ + k0);
            rb[i] = *(const bf16x8*)(Wp + (size_t)i * 32 * K_ + k0);
        }
    };
    loadin(0);

    for (int k0 = 0; k0 < K_; k0 += 64) {
        __syncthreads();
        #pragma unroll
        for (int i = 0; i < 4; ++i) {
            const int row = i * 32 + srow;
            const int sc = (scol * 2) ^ ((row & 7) << 4);
            *(bf16x8*)((char*)As + row * 128 + sc) = ra[i];
            *(bf16x8*)((char*)Bs + row * 128 + sc) = rb[i];
        }
        __syncthreads();
        if (k0 < K_ - 64) loadin(k0 + 64);
        #pragma unroll
        for (int kk = 0; kk < 2; ++kk) {
            bf16x8 af[4], bfr[4];
            #pragma unroll
            for (int mi = 0; mi < 4; ++mi) {
                const int row = wm + mi * 16 + c;
                const int sc = (kk * 64 + u * 16) ^ ((row & 7) << 4);
                af[mi] = *(const bf16x8*)((char*)As + row * 128 + sc);
            }
            #pragma unroll
            for (int ni = 0; ni < 4; ++ni) {
                const int row = wn + ni * 16 + c;
                const int sc = (kk * 64 + u * 16) ^ ((row & 7) << 4);
                bfr[ni] = *(const bf16x8*)((char*)Bs + row * 128 + sc);
            }
            #pragma unroll
            for (int mi = 0; mi < 4; ++mi)
                #pragma unroll
                for (int ni = 0; ni < 4; ++ni)
                    acc[mi][ni] = __builtin_amdgcn_mfma_f32_16x16x32_bf16(
                        af[mi], bfr[ni], acc[mi][ni], 0, 0, 0);
        }
    }

    if constexpr (TYPE == 1) {
        #pragma unroll
        for (int mi = 0; mi < 4; ++mi)
            #pragma unroll
            for (int ni = 0; ni < 4; ++ni)
                #pragma unroll
                for (int r = 0; r < 4; ++r)
                    fout[(size_t)(bm + wm + 16*mi + 4*u + r) * HID_ + (bn + wn + 16*ni + c)] =
                        acc[mi][ni][r];
    } else {
        const int sec = bn >> 10;
        const int h = ((bn + wn) & 1023) >> 6;
        if (sec == 2) {
            #pragma unroll
            for (int mi = 0; mi < 4; ++mi)
                #pragma unroll
                for (int r = 0; r < 4; ++r) {
                    const int mg = bm + wm + 16*mi + 4*u + r;
                    const int bb = mg >> 11, t = mg & 2047;
                    const int tk = (t & ~12) | ((t & 4) << 1) | ((t & 8) >> 1);  // kappa
                    #pragma unroll
                    for (int ni = 0; ni < 4; ++ni)
                        vtb[((size_t)(bb*16 + h) * 64 + 16*ni + c) * 2048 + tk] =
                            f2bf(acc[mi][ni][r]);
                }
        } else {
            unsigned short* ob = sec ? kb : qb;
            const float qsc = sec ? 1.0f : (0.125f * LOG2E);   // q in log2 domain
            #pragma unroll
            for (int mi = 0; mi < 4; ++mi)
                #pragma unroll
                for (int r = 0; r < 4; ++r) {
                    const int mg = bm + wm + 16*mi + 4*u + r;
                    const int bb = mg >> 11, t = mg & 2047;
                    const size_t base = ((size_t)(bb*16 + h) * 2048 + t) * 64;
                    #pragma unroll
                    for (int ni = 0; ni < 2; ++ni) {
                        const int dlo = 16*ni + c;
                        const float cv = cs[t*64 + dlo], sv = sn[t*64 + dlo];
                        const float Aa = acc[mi][ni][r], Bb = acc[mi][ni+2][r];
                        ob[base + dlo]      = f2bf((Aa*cv - Bb*sv) * qsc);
                        ob[base + dlo + 32] = f2bf((Bb*cv + Aa*sv) * qsc);
                    }
                }
        }
    }
}

// ---------------- attn16 (unchanged; best measured 61.5us) ----------------
__global__ __launch_bounds__(256)
void attn16(const unsigned short* __restrict__ q, const unsigned short* __restrict__ k,
            const unsigned short* __restrict__ vt, unsigned short* __restrict__ ab) {
    const int raw = blockIdx.x;                          // 1024 blocks
    const int bh     = (raw & 7) + 8 * ((raw >> 3) & 3); // same-bh -> same XCD
    const int qchunk = 31 - (raw >> 5);                  // heavy blocks first
    const int tid = threadIdx.x;
    const int wid = tid >> 6, lane = tid & 63;
    const int h = lane >> 5, c = lane & 31;
    const int b = bh >> 4, hh = bh & 15;
    const int q0 = qchunk * 64;
    const int qgcA = q0 + c, qgcB = q0 + 32 + c;
    const int stAd = 2 * qchunk;                         // tile A diag subtile
    const int NT   = 2 * qchunk + 2;                     // KV subtiles (tile B diag = NT-1)
    const unsigned short* qp = q  + (size_t)bh * (T_*64);
    const unsigned short* kp = k  + (size_t)bh * (T_*64);
    const unsigned short* vp = vt + (size_t)bh * (64*T_);

    const int kloff  = c * 64 + 8 * h;
    const int vloff0 = c * 2048 + 8 * h;
    const int vloff1 = vloff0 + 32 * 2048;

    bf16x8 qfA[4], qfB[4];
    {
        const unsigned short* qrowA = qp + (q0 + c) * 64 + 8 * h;
        const unsigned short* qrowB = qrowA + 32 * 64;
        #pragma unroll
        for (int s = 0; s < 4; ++s) {
            qfA[s] = *(const bf16x8*)(qrowA + s * 16);
            qfB[s] = *(const bf16x8*)(qrowB + s * 16);
        }
    }

    f32x16 OA0 = {}, OA1 = {}, OB0 = {}, OB1 = {};
    float mA = -1e30f, lA = 0.f, mB = -1e30f, lB = 0.f;

    auto loadK = [&](bf16x8 (&kf)[4], int st) {
        const unsigned short* kst = kp + (st << 11);
        #pragma unroll
        for (int s = 0; s < 4; ++s)
            kf[s] = *(const bf16x8*)(kst + kloff + s * 16);
    };

    auto process = [&](bf16x8 (&kf)[4], int st) {
        const int kvs = st << 5;
        const unsigned short* vst = vp + (st << 5);
        bf16x8 vf0 = *(const bf16x8*)(vst + vloff0);
        bf16x8 vf1 = *(const bf16x8*)(vst + vloff0 + 16);
        bf16x8 vf2 = *(const bf16x8*)(vst + vloff1);
        bf16x8 vf3 = *(const bf16x8*)(vst + vloff1 + 16);
        const bool doA = (st <= stAd);                   // uniform
        float pA[16], pB[16];
        float mxA = -1e30f, mxB;
        if (doA) {
            __builtin_amdgcn_s_setprio(1);
            f32x16 sa = {};
            #pragma unroll
            for (int s = 0; s < 4; ++s)
                sa = __builtin_amdgcn_mfma_f32_32x32x16_bf16(kf[s], qfA[s], sa, 0, 0, 0);
            __builtin_amdgcn_s_setprio(0);
            #pragma unroll
            for (int r = 0; r < 16; ++r) pA[r] = sa[r];
            if (st == stAd) {
                #pragma unroll
                for (int r = 0; r < 16; ++r) {
                    const int kk = kvs + (r & 3) + 8 * (r >> 2) + 4 * h;
                    if (kk > qgcA) pA[r] = -1e30f;
                }
            }
            const float a0 = fmaxf(fmaxf(pA[0],  pA[1]),  pA[2]);
            const float a1 = fmaxf(fmaxf(pA[3],  pA[4]),  pA[5]);
            const float a2 = fmaxf(fmaxf(pA[6],  pA[7]),  pA[8]);
            const float a3 = fmaxf(fmaxf(pA[9],  pA[10]), pA[11]);
            const float a4 = fmaxf(fmaxf(pA[12], pA[13]), pA[14]);
            mxA = fmaxf(fmaxf(fmaxf(a0, a1), fmaxf(a2, a3)), fmaxf(a4, pA[15]));
        }
        {
            __builtin_amdgcn_s_setprio(1);
            f32x16 sa = {};
            #pragma unroll
            for (int s = 0; s < 4; ++s)
                sa = __builtin_amdgcn_mfma_f32_32x32x16_bf16(kf[s], qfB[s], sa, 0, 0, 0);
            __builtin_amdgcn_s_setprio(0);
            #pragma unroll
            for (int r = 0; r < 16; ++r) pB[r] = sa[r];
            if (st == NT - 1) {
                #pragma unroll
                for (int r = 0; r < 16; ++r) {
                    const int kk = kvs + (r & 3) + 8 * (r >> 2) + 4 * h;
                    if (kk > qgcB) pB[r] = -1e30f;
                }
            }
            const float a0 = fmaxf(fmaxf(pB[0],  pB[1]),  pB[2]);
            const float a1 = fmaxf(fmaxf(pB[3],  pB[4]),  pB[5]);
            const float a2 = fmaxf(fmaxf(pB[6],  pB[7]),  pB[8]);
            const float a3 = fmaxf(fmaxf(pB[9],  pB[10]), pB[11]);
            const float a4 = fmaxf(fmaxf(pB[12], pB[13]), pB[14]);
            mxB = fmaxf(fmaxf(fmaxf(a0, a1), fmaxf(a2, a3)), fmaxf(a4, pB[15]));
        }
        // kf's last read was the B QK^T — prefetch st+4 into the SAME buffer now;
        // the load is covered by the softmax+PV below (~600cy).
        if (st + 4 < NT) loadK(kf, st + 4);
        if (!__all(fmaxf(mxA - mA, mxB - mB) <= 8.0f)) {
            if (doA) {
                const float fx = fmaxf(mxA, __shfl_xor(mxA, 32));
                const float mn = fmaxf(mA, fx);
                const float f = __builtin_amdgcn_exp2f(mA - mn);
                mA = mn; lA *= f;
                #pragma unroll
                for (int r = 0; r < 16; ++r) { OA0[r] *= f; OA1[r] *= f; }
            }
            {
                const float fx = fmaxf(mxB, __shfl_xor(mxB, 32));
                const float mn = fmaxf(mB, fx);
                const float f = __builtin_amdgcn_exp2f(mB - mn);
                mB = mn; lB *= f;
                #pragma unroll
                for (int r = 0; r < 16; ++r) { OB0[r] *= f; OB1[r] *= f; }
            }
        }
        if (doA) {
            float ps = 0.f;
            #pragma unroll
            for (int r = 0; r < 16; ++r) {
                pA[r] = __builtin_amdgcn_exp2f(pA[r] - mA);
                ps += pA[r];
            }
            lA += ps;
            u32x4 B0w = { pkt(pA[0],  pA[1]),  pkt(pA[2],  pA[3]),
                          pkt(pA[4],  pA[5]),  pkt(pA[6],  pA[7])  };
            u32x4 B1w = { pkt(pA[8],  pA[9]),  pkt(pA[10], pA[11]),
                          pkt(pA[12], pA[13]), pkt(pA[14], pA[15]) };
            bf16x8 PB0 = __builtin_bit_cast(bf16x8, B0w);
            bf16x8 PB1 = __builtin_bit_cast(bf16x8, B1w);
            __builtin_amdgcn_s_setprio(1);
            OA0 = __builtin_amdgcn_mfma_f32_32x32x16_bf16(vf0, PB0, OA0, 0, 0, 0);
            OA0 = __builtin_amdgcn_mfma_f32_32x32x16_bf16(vf1, PB1, OA0, 0, 0, 0);
            OA1 = __builtin_amdgcn_mfma_f32_32x32x16_bf16(vf2, PB0, OA1, 0, 0, 0);
            OA1 = __builtin_amdgcn_mfma_f32_32x32x16_bf16(vf3, PB1, OA1, 0, 0, 0);
            __builtin_amdgcn_s_setprio(0);
        }
        {
            float ps = 0.f;
            #pragma unroll
            for (int r = 0; r < 16; ++r) {
                pB[r] = __builtin_amdgcn_exp2f(pB[r] - mB);
                ps += pB[r];
            }
            lB += ps;
            u32x4 B0w = { pkt(pB[0],  pB[1]),  pkt(pB[2],  pB[3]),
                          pkt(pB[4],  pB[5]),  pkt(pB[6],  pB[7])  };
            u32x4 B1w = { pkt(pB[8],  pB[9]),  pkt(pB[10], pB[11]),
                          pkt(pB[12], pB[13]), pkt(pB[14], pB[15]) };
            bf16x8 PB0 = __builtin_bit_cast(bf16x8, B0w);
            bf16x8 PB1 = __builtin_bit_cast(bf16x8, B1w);
            __builtin_amdgcn_s_setprio(1);
            OB0 = __builtin_amdgcn_mfma_f32_32x32x16_bf16(vf0, PB0, OB0, 0, 0, 0);
            OB0 = __builtin_amdgcn_mfma_f32_32x32x16_bf16(vf1, PB1, OB0, 0, 0, 0);
            OB1 = __builtin_amdgcn_mfma_f32_32x32x16_bf16(vf2, PB0, OB1, 0, 0, 0);
            OB1 = __builtin_amdgcn_mfma_f32_32x32x16_bf16(vf3, PB1, OB1, 0, 0, 0);
            __builtin_amdgcn_s_setprio(0);
        }
    };

    bf16x8 kf_[4];
    if (wid < NT) {
        loadK(kf_, wid);
        for (int st = wid; st < NT; st += 4)
            process(kf_, st);
    }
    lA += __shfl_xor(lA, 32);
    lB += __shfl_xor(lB, 32);

    // ---- merge the 4 wave-partials in LDS (bf16-packed, stride 34 u32) ----
    __shared__ unsigned OSu[4][64 * 34];
    __shared__ float mS[4][64], lS[4][64];
    if (h == 0) {
        mS[wid][c] = mA;      lS[wid][c] = lA;
        mS[wid][32 + c] = mB; lS[wid][32 + c] = lB;
    }
    {
        unsigned* os = &OSu[wid][0];
        const int rbA = c * 34 + 2 * h;
        const int rbB = (32 + c) * 34 + 2 * h;
        #pragma unroll
        for (int j = 0; j < 4; ++j) {
            os[rbA + 4*j]          = pk2(OA0[4*j],   OA0[4*j+1]);
            os[rbA + 4*j + 1]      = pk2(OA0[4*j+2], OA0[4*j+3]);
            os[rbA + 16 + 4*j]     = pk2(OA1[4*j],   OA1[4*j+1]);
            os[rbA + 16 + 4*j + 1] = pk2(OA1[4*j+2], OA1[4*j+3]);
            os[rbB + 4*j]          = pk2(OB0[4*j],   OB0[4*j+1]);
            os[rbB + 4*j + 1]      = pk2(OB0[4*j+2], OB0[4*j+3]);
            os[rbB + 16 + 4*j]     = pk2(OB1[4*j],   OB1[4*j+1]);
            os[rbB + 16 + 4*j + 1] = pk2(OB1[4*j+2], OB1[4*j+3]);
        }
    }
    __syncthreads();

    const int ql = tid & 63, ug = (tid >> 6) * 8;   // 8 u32 = 16 d per thread
    const float M = fmaxf(fmaxf(mS[0][ql], mS[1][ql]), fmaxf(mS[2][ql], mS[3][ql]));
    float acc[16] = {};
    float L = 0.f;
    #pragma unroll
    for (int w2 = 0; w2 < 4; ++w2) {
        const float sc = __builtin_amdgcn_exp2f(mS[w2][ql] - M);
        L += lS[w2][ql] * sc;
        u32x4 pa = *(u32x4*)&OSu[w2][ql * 34 + ug];
        u32x4 pb = *(u32x4*)&OSu[w2][ql * 34 + ug + 4];
        #pragma unroll
        for (int t = 0; t < 4; ++t) {
            acc[2*t]     += __builtin_bit_cast(float, pa[t] << 16) * sc;
            acc[2*t+1]   += __builtin_bit_cast(float, pa[t] & 0xffff0000u) * sc;
            acc[8+2*t]   += __builtin_bit_cast(float, pb[t] << 16) * sc;
            acc[8+2*t+1] += __builtin_bit_cast(float, pb[t] & 0xffff0000u) * sc;
        }
    }
    const float inv = 1.0f / L;
    uint4 ov0, ov1;
    ov0.x = pk2(acc[0]*inv,  acc[1]*inv);
    ov0.y = pk2(acc[2]*inv,  acc[3]*inv);
    ov0.z = pk2(acc[4]*inv,  acc[5]*inv);
    ov0.w = pk2(acc[6]*inv,  acc[7]*inv);
    ov1.x = pk2(acc[8]*inv,  acc[9]*inv);
    ov1.y = pk2(acc[10]*inv, acc[11]*inv);
    ov1.z = pk2(acc[12]*inv, acc[13]*inv);
    ov1.w = pk2(acc[14]*inv, acc[15]*inv);
    unsigned short* orow = ab + ((size_t)(b * T_) + q0 + ql) * HID_ + hh * 64 + ug * 2;
    *(uint4*)orow       = ov0;
    *(uint4*)(orow + 8) = ov1;
}

extern "C" void kernel_launch(void* const* d_in, const int* in_sizes, int n_in,
                              void* d_out, int out_size, void* d_ws, size_t ws_size,
                              hipStream_t stream) {
    const float* x  = (const float*)d_in[0];
    const float* Wq = (const float*)d_in[1];
    const float* Wk = (const float*)d_in[2];
    const float* Wv = (const float*)d_in[3];
    const float* Wo = (const float*)d_in[4];
    const float* cs = (const float*)d_in[5];
    const float* sn = (const float*)d_in[6];
    char* wsb = (char*)d_ws;
    unsigned short* xb  = (unsigned short*)(wsb);                  // 8 MB
    unsigned short* wqb = (unsigned short*)(wsb + (8u  << 20));    // 2 MB each
    unsigned short* wkb = (unsigned short*)(wsb + (10u << 20));
    unsigned short* wvb = (unsigned short*)(wsb + (12u << 20));
    unsigned short* wob = (unsigned short*)(wsb + (14u << 20));
    unsigned short* qb  = (unsigned short*)(wsb + (16u << 20));
    unsigned short* kb  = (unsigned short*)(wsb + (24u << 20));
    unsigned short* vtb = (unsigned short*)(wsb + (32u << 20));
    unsigned short* ab  = (unsigned short*)(wsb + (40u << 20));

    cast_all<<<4096, 256, 0, stream>>>(x, Wq, Wk, Wv, Wo, xb, wqb, wkb, wvb, wob);

    gemm_k<0><<<768, 256, 0, stream>>>(
        xb, wqb, wkb, wvb, cs, sn, qb, kb, vtb, nullptr);
    attn16<<<1024, 256, 0, stream>>>(qb, kb, vtb, ab);
    gemm_k<1><<<256, 256, 0, stream>>>(
        ab, wob, nullptr, nullptr, nullptr, nullptr,
        nullptr, nullptr, nullptr, (float*)d_out);
}

// Round 22
// 116.702 us; speedup vs baseline: 1.2227x; 1.0046x over previous
//
#include <hip/hip_runtime.h>
#include <hip/hip_bf16.h>

#define B_   2
#define T_   2048
#define HID_ 1024
#define NH_  16
#define HD_  64
#define K_   1024
#define M_   (B_*T_)

typedef __attribute__((ext_vector_type(8)))  short bf16x8;
typedef __attribute__((ext_vector_type(4)))  float f32x4;
typedef __attribute__((ext_vector_type(16))) float f32x16;
typedef __attribute__((ext_vector_type(4)))  unsigned int u32x4;
typedef __attribute__((ext_vector_type(2)))  unsigned int u32x2;

#define LOG2E 1.44269504088896340736f

__device__ inline unsigned short f2bf(float f) {
    __hip_bfloat16 h = __float2bfloat16(f);
    return __builtin_bit_cast(unsigned short, h);
}
__device__ inline unsigned int pk2(float a, float b) {
    return (unsigned int)f2bf(a) | ((unsigned int)f2bf(b) << 16);
}
// truncation pack: (a>>16) | (b & 0xffff0000) in ONE v_perm_b32
__device__ inline unsigned int pkt(float a, float b) {
    return __builtin_amdgcn_perm(__builtin_bit_cast(unsigned, a),
                                 __builtin_bit_cast(unsigned, b), 0x03020706u);
}
__device__ inline bf16x8 cvt8(float4 a, float4 b) {
    bf16x8 r;
    r[0]=(short)f2bf(a.x); r[1]=(short)f2bf(a.y); r[2]=(short)f2bf(a.z); r[3]=(short)f2bf(a.w);
    r[4]=(short)f2bf(b.x); r[5]=(short)f2bf(b.y); r[6]=(short)f2bf(b.z); r[7]=(short)f2bf(b.w);
    return r;
}

// ---------------- fp32 -> bf16 cast, single launch (x + 4 weights) ----------------
__global__ __launch_bounds__(256)
void cast_all(const float* __restrict__ x,
              const float* __restrict__ W0, const float* __restrict__ W1,
              const float* __restrict__ W2, const float* __restrict__ W3,
              unsigned short* __restrict__ xo,
              unsigned short* __restrict__ o0, unsigned short* __restrict__ o1,
              unsigned short* __restrict__ o2, unsigned short* __restrict__ o3) {
    const int blk = blockIdx.x;
    const float* in;
    unsigned short* out;
    int i;
    if (blk < 2048) {
        in = x; out = xo; i = blk * 256 + threadIdx.x;
    } else {
        const int wb = blk - 2048, sec = wb >> 9;
        in  = (sec == 0) ? W0 : (sec == 1) ? W1 : (sec == 2) ? W2 : W3;
        out = (sec == 0) ? o0 : (sec == 1) ? o1 : (sec == 2) ? o2 : o3;
        i = (wb & 511) * 256 + threadIdx.x;
    }
    float4 a = ((const float4*)in)[2*i], b = ((const float4*)in)[2*i + 1];
    ((bf16x8*)out)[i] = cvt8(a, b);
}

// ---------------- bf16 GEMM-NT: reg-staged + XOR-swizzled LDS ----------------
// TYPE 0: 128x128 tile, grid 768 (3 blocks/CU). TYPE 1: 128x64 tile, grid 512
// (2 blocks/CU = 2 waves/SIMD — fixes the old 256-block 1-wave/SIMD Wo launch).
// BN parametrizes the N-tile; TYPE 0 path is byte-identical to the proven kernel.
template<int TYPE>
__global__ __launch_bounds__(256)
void gemm_k(const unsigned short* __restrict__ A, const unsigned short* __restrict__ W0,
            const unsigned short* __restrict__ W1, const unsigned short* __restrict__ W2,
            const float* __restrict__ cs, const float* __restrict__ sn,
            unsigned short* __restrict__ qb, unsigned short* __restrict__ kb,
            unsigned short* __restrict__ vtb, float* __restrict__ fout) {
    constexpr int BN = (TYPE == 1) ? 64 : 128;   // N-tile width
    constexpr int NB = BN / 32;                  // B row-segments per staging pass
    constexpr int NF = BN / 32;                  // B fragments per wave (BN/2 / 16)
    __shared__ unsigned short As[128*64];
    __shared__ unsigned short Bs[BN*64];
    const int tid = threadIdx.x;
    const int w = tid >> 6, lane = tid & 63;
    const int u = lane >> 4, c = lane & 15;
    const int bid = blockIdx.x;
    const int xcd = bid & 7, idx = bid >> 3;
    int bmi, bni;
    if constexpr (TYPE == 0) {          // 32 x 24 tiles, 8 XCD x (8bm x 12bn)
        bmi = (xcd & 3) * 8 + (idx & 7);
        bni = (xcd >> 2) * 12 + (idx >> 3);
    } else {                            // 32 x 16 tiles, 8 XCD x (8bm x 8bn)
        bmi = (xcd & 3) * 8 + (idx & 7);
        bni = (xcd >> 2) * 8 + (idx >> 3);
    }
    const int bm = bmi * 128, bn = bni * BN;
    const int wm = (w & 1) * 64, wn = (w >> 1) * (BN / 2);
    const int srow = tid >> 3, scol = (tid & 7) << 3;

    const unsigned short* Wsec;
    int wrowbase;
    if constexpr (TYPE == 0) {
        const int sec = bn >> 10;
        Wsec = (sec == 0) ? W0 : ((sec == 1) ? W1 : W2);
        wrowbase = bn & 1023;
    } else {
        Wsec = W0;
        wrowbase = bn;
    }
    const unsigned short* Wp = Wsec + (size_t)(wrowbase + srow) * K_ + scol;
    const unsigned short* Ap = A + (size_t)(bm + srow) * K_ + scol;

    f32x4 acc[4][NF] = {};
    bf16x8 ra[4], rb[NB];

    auto loadin = [&](int k0) {
        #pragma unroll
        for (int i = 0; i < 4; ++i)
            ra[i] = *(const bf16x8*)(Ap + (size_t)i * 32 * K_ + k0);
        #pragma unroll
        for (int i = 0; i < NB; ++i)
            rb[i] = *(const bf16x8*)(Wp + (size_t)i * 32 * K_ + k0);
    };
    loadin(0);

    for (int k0 = 0; k0 < K_; k0 += 64) {
        __syncthreads();
        #pragma unroll
        for (int i = 0; i < 4; ++i) {
            const int row = i * 32 + srow;
            const int sc = (scol * 2) ^ ((row & 7) << 4);
            *(bf16x8*)((char*)As + row * 128 + sc) = ra[i];
        }
        #pragma unroll
        for (int i = 0; i < NB; ++i) {
            const int row = i * 32 + srow;
            const int sc = (scol * 2) ^ ((row & 7) << 4);
            *(bf16x8*)((char*)Bs + row * 128 + sc) = rb[i];
        }
        __syncthreads();
        if (k0 < K_ - 64) loadin(k0 + 64);
        #pragma unroll
        for (int kk = 0; kk < 2; ++kk) {
            bf16x8 af[4], bfr[NF];
            #pragma unroll
            for (int mi = 0; mi < 4; ++mi) {
                const int row = wm + mi * 16 + c;
                const int sc = (kk * 64 + u * 16) ^ ((row & 7) << 4);
                af[mi] = *(const bf16x8*)((char*)As + row * 128 + sc);
            }
            #pragma unroll
            for (int ni = 0; ni < NF; ++ni) {
                const int row = wn + ni * 16 + c;
                const int sc = (kk * 64 + u * 16) ^ ((row & 7) << 4);
                bfr[ni] = *(const bf16x8*)((char*)Bs + row * 128 + sc);
            }
            #pragma unroll
            for (int mi = 0; mi < 4; ++mi)
                #pragma unroll
                for (int ni = 0; ni < NF; ++ni)
                    acc[mi][ni] = __builtin_amdgcn_mfma_f32_16x16x32_bf16(
                        af[mi], bfr[ni], acc[mi][ni], 0, 0, 0);
        }
    }

    if constexpr (TYPE == 1) {
        #pragma unroll
        for (int mi = 0; mi < 4; ++mi)
            #pragma unroll
            for (int ni = 0; ni < NF; ++ni)
                #pragma unroll
                for (int r = 0; r < 4; ++r)
                    fout[(size_t)(bm + wm + 16*mi + 4*u + r) * HID_ + (bn + wn + 16*ni + c)] =
                        acc[mi][ni][r];
    } else {
        const int sec = bn >> 10;
        const int h = ((bn + wn) & 1023) >> 6;
        if (sec == 2) {
            #pragma unroll
            for (int mi = 0; mi < 4; ++mi)
                #pragma unroll
                for (int r = 0; r < 4; ++r) {
                    const int mg = bm + wm + 16*mi + 4*u + r;
                    const int bb = mg >> 11, t = mg & 2047;
                    const int tk = (t & ~12) | ((t & 4) << 1) | ((t & 8) >> 1);  // kappa
                    #pragma unroll
                    for (int ni = 0; ni < 4; ++ni)
                        vtb[((size_t)(bb*16 + h) * 64 + 16*ni + c) * 2048 + tk] =
                            f2bf(acc[mi][ni][r]);
                }
        } else {
            unsigned short* ob = sec ? kb : qb;
            const float qsc = sec ? 1.0f : (0.125f * LOG2E);   // q in log2 domain
            #pragma unroll
            for (int mi = 0; mi < 4; ++mi)
                #pragma unroll
                for (int r = 0; r < 4; ++r) {
                    const int mg = bm + wm + 16*mi + 4*u + r;
                    const int bb = mg >> 11, t = mg & 2047;
                    const size_t base = ((size_t)(bb*16 + h) * 2048 + t) * 64;
                    #pragma unroll
                    for (int ni = 0; ni < 2; ++ni) {
                        const int dlo = 16*ni + c;
                        const float cv = cs[t*64 + dlo], sv = sn[t*64 + dlo];
                        const float Aa = acc[mi][ni][r], Bb = acc[mi][ni+2][r];
                        ob[base + dlo]      = f2bf((Aa*cv - Bb*sv) * qsc);
                        ob[base + dlo + 32] = f2bf((Bb*cv + Aa*sv) * qsc);
                    }
                }
        }
    }
}

// ---------------- attn16 (unchanged; best measured 61.5us) ----------------
__global__ __launch_bounds__(256)
void attn16(const unsigned short* __restrict__ q, const unsigned short* __restrict__ k,
            const unsigned short* __restrict__ vt, unsigned short* __restrict__ ab) {
    const int raw = blockIdx.x;                          // 1024 blocks
    const int bh     = (raw & 7) + 8 * ((raw >> 3) & 3); // same-bh -> same XCD
    const int qchunk = 31 - (raw >> 5);                  // heavy blocks first
    const int tid = threadIdx.x;
    const int wid = tid >> 6, lane = tid & 63;
    const int h = lane >> 5, c = lane & 31;
    const int b = bh >> 4, hh = bh & 15;
    const int q0 = qchunk * 64;
    const int qgcA = q0 + c, qgcB = q0 + 32 + c;
    const int stAd = 2 * qchunk;                         // tile A diag subtile
    const int NT   = 2 * qchunk + 2;                     // KV subtiles (tile B diag = NT-1)
    const unsigned short* qp = q  + (size_t)bh * (T_*64);
    const unsigned short* kp = k  + (size_t)bh * (T_*64);
    const unsigned short* vp = vt + (size_t)bh * (64*T_);

    const int kloff  = c * 64 + 8 * h;
    const int vloff0 = c * 2048 + 8 * h;
    const int vloff1 = vloff0 + 32 * 2048;

    bf16x8 qfA[4], qfB[4];
    {
        const unsigned short* qrowA = qp + (q0 + c) * 64 + 8 * h;
        const unsigned short* qrowB = qrowA + 32 * 64;
        #pragma unroll
        for (int s = 0; s < 4; ++s) {
            qfA[s] = *(const bf16x8*)(qrowA + s * 16);
            qfB[s] = *(const bf16x8*)(qrowB + s * 16);
        }
    }

    f32x16 OA0 = {}, OA1 = {}, OB0 = {}, OB1 = {};
    float mA = -1e30f, lA = 0.f, mB = -1e30f, lB = 0.f;

    auto loadK = [&](bf16x8 (&kf)[4], int st) {
        const unsigned short* kst = kp + (st << 11);
        #pragma unroll
        for (int s = 0; s < 4; ++s)
            kf[s] = *(const bf16x8*)(kst + kloff + s * 16);
    };

    auto process = [&](bf16x8 (&kf)[4], int st) {
        const int kvs = st << 5;
        const unsigned short* vst = vp + (st << 5);
        bf16x8 vf0 = *(const bf16x8*)(vst + vloff0);
        bf16x8 vf1 = *(const bf16x8*)(vst + vloff0 + 16);
        bf16x8 vf2 = *(const bf16x8*)(vst + vloff1);
        bf16x8 vf3 = *(const bf16x8*)(vst + vloff1 + 16);
        const bool doA = (st <= stAd);                   // uniform
        float pA[16], pB[16];
        float mxA = -1e30f, mxB;
        if (doA) {
            __builtin_amdgcn_s_setprio(1);
            f32x16 sa = {};
            #pragma unroll
            for (int s = 0; s < 4; ++s)
                sa = __builtin_amdgcn_mfma_f32_32x32x16_bf16(kf[s], qfA[s], sa, 0, 0, 0);
            __builtin_amdgcn_s_setprio(0);
            #pragma unroll
            for (int r = 0; r < 16; ++r) pA[r] = sa[r];
            if (st == stAd) {
                #pragma unroll
                for (int r = 0; r < 16; ++r) {
                    const int kk = kvs + (r & 3) + 8 * (r >> 2) + 4 * h;
                    if (kk > qgcA) pA[r] = -1e30f;
                }
            }
            const float a0 = fmaxf(fmaxf(pA[0],  pA[1]),  pA[2]);
            const float a1 = fmaxf(fmaxf(pA[3],  pA[4]),  pA[5]);
            const float a2 = fmaxf(fmaxf(pA[6],  pA[7]),  pA[8]);
            const float a3 = fmaxf(fmaxf(pA[9],  pA[10]), pA[11]);
            const float a4 = fmaxf(fmaxf(pA[12], pA[13]), pA[14]);
            mxA = fmaxf(fmaxf(fmaxf(a0, a1), fmaxf(a2, a3)), fmaxf(a4, pA[15]));
        }
        {
            __builtin_amdgcn_s_setprio(1);
            f32x16 sa = {};
            #pragma unroll
            for (int s = 0; s < 4; ++s)
                sa = __builtin_amdgcn_mfma_f32_32x32x16_bf16(kf[s], qfB[s], sa, 0, 0, 0);
            __builtin_amdgcn_s_setprio(0);
            #pragma unroll
            for (int r = 0; r < 16; ++r) pB[r] = sa[r];
            if (st == NT - 1) {
                #pragma unroll
                for (int r = 0; r < 16; ++r) {
                    const int kk = kvs + (r & 3) + 8 * (r >> 2) + 4 * h;
                    if (kk > qgcB) pB[r] = -1e30f;
                }
            }
            const float a0 = fmaxf(fmaxf(pB[0],  pB[1]),  pB[2]);
            const float a1 = fmaxf(fmaxf(pB[3],  pB[4]),  pB[5]);
            const float a2 = fmaxf(fmaxf(pB[6],  pB[7]),  pB[8]);
            const float a3 = fmaxf(fmaxf(pB[9],  pB[10]), pB[11]);
            const float a4 = fmaxf(fmaxf(pB[12], pB[13]), pB[14]);
            mxB = fmaxf(fmaxf(fmaxf(a0, a1), fmaxf(a2, a3)), fmaxf(a4, pB[15]));
        }
        // kf's last read was the B QK^T — prefetch st+4 into the SAME buffer now;
        // the load is covered by the softmax+PV below (~600cy).
        if (st + 4 < NT) loadK(kf, st + 4);
        if (!__all(fmaxf(mxA - mA, mxB - mB) <= 8.0f)) {
            if (doA) {
                const float fx = fmaxf(mxA, __shfl_xor(mxA, 32));
                const float mn = fmaxf(mA, fx);
                const float f = __builtin_amdgcn_exp2f(mA - mn);
                mA = mn; lA *= f;
                #pragma unroll
                for (int r = 0; r < 16; ++r) { OA0[r] *= f; OA1[r] *= f; }
            }
            {
                const float fx = fmaxf(mxB, __shfl_xor(mxB, 32));
                const float mn = fmaxf(mB, fx);
                const float f = __builtin_amdgcn_exp2f(mB - mn);
                mB = mn; lB *= f;
                #pragma unroll
                for (int r = 0; r < 16; ++r) { OB0[r] *= f; OB1[r] *= f; }
            }
        }
        if (doA) {
            float ps = 0.f;
            #pragma unroll
            for (int r = 0; r < 16; ++r) {
                pA[r] = __builtin_amdgcn_exp2f(pA[r] - mA);
                ps += pA[r];
            }
            lA += ps;
            u32x4 B0w = { pkt(pA[0],  pA[1]),  pkt(pA[2],  pA[3]),
                          pkt(pA[4],  pA[5]),  pkt(pA[6],  pA[7])  };
            u32x4 B1w = { pkt(pA[8],  pA[9]),  pkt(pA[10], pA[11]),
                          pkt(pA[12], pA[13]), pkt(pA[14], pA[15]) };
            bf16x8 PB0 = __builtin_bit_cast(bf16x8, B0w);
            bf16x8 PB1 = __builtin_bit_cast(bf16x8, B1w);
            __builtin_amdgcn_s_setprio(1);
            OA0 = __builtin_amdgcn_mfma_f32_32x32x16_bf16(vf0, PB0, OA0, 0, 0, 0);
            OA0 = __builtin_amdgcn_mfma_f32_32x32x16_bf16(vf1, PB1, OA0, 0, 0, 0);
            OA1 = __builtin_amdgcn_mfma_f32_32x32x16_bf16(vf2, PB0, OA1, 0, 0, 0);
            OA1 = __builtin_amdgcn_mfma_f32_32x32x16_bf16(vf3, PB1, OA1, 0, 0, 0);
            __builtin_amdgcn_s_setprio(0);
        }
        {
            float ps = 0.f;
            #pragma unroll
            for (int r = 0; r < 16; ++r) {
                pB[r] = __builtin_amdgcn_exp2f(pB[r] - mB);
                ps += pB[r];
            }
            lB += ps;
            u32x4 B0w = { pkt(pB[0],  pB[1]),  pkt(pB[2],  pB[3]),
                          pkt(pB[4],  pB[5]),  pkt(pB[6],  pB[7])  };
            u32x4 B1w = { pkt(pB[8],  pB[9]),  pkt(pB[10], pB[11]),
                          pkt(pB[12], pB[13]), pkt(pB[14], pB[15]) };
            bf16x8 PB0 = __builtin_bit_cast(bf16x8, B0w);
            bf16x8 PB1 = __builtin_bit_cast(bf16x8, B1w);
            __builtin_amdgcn_s_setprio(1);
            OB0 = __builtin_amdgcn_mfma_f32_32x32x16_bf16(vf0, PB0, OB0, 0, 0, 0);
            OB0 = __builtin_amdgcn_mfma_f32_32x32x16_bf16(vf1, PB1, OB0, 0, 0, 0);
            OB1 = __builtin_amdgcn_mfma_f32_32x32x16_bf16(vf2, PB0, OB1, 0, 0, 0);
            OB1 = __builtin_amdgcn_mfma_f32_32x32x16_bf16(vf3, PB1, OB1, 0, 0, 0);
            __builtin_amdgcn_s_setprio(0);
        }
    };

    bf16x8 kf_[4];
    if (wid < NT) {
        loadK(kf_, wid);
        for (int st = wid; st < NT; st += 4)
            process(kf_, st);
    }
    lA += __shfl_xor(lA, 32);
    lB += __shfl_xor(lB, 32);

    // ---- merge the 4 wave-partials in LDS (bf16-packed, stride 34 u32) ----
    __shared__ unsigned OSu[4][64 * 34];
    __shared__ float mS[4][64], lS[4][64];
    if (h == 0) {
        mS[wid][c] = mA;      lS[wid][c] = lA;
        mS[wid][32 + c] = mB; lS[wid][32 + c] = lB;
    }
    {
        unsigned* os = &OSu[wid][0];
        const int rbA = c * 34 + 2 * h;
        const int rbB = (32 + c) * 34 + 2 * h;
        #pragma unroll
        for (int j = 0; j < 4; ++j) {
            os[rbA + 4*j]          = pk2(OA0[4*j],   OA0[4*j+1]);
            os[rbA + 4*j + 1]      = pk2(OA0[4*j+2], OA0[4*j+3]);
            os[rbA + 16 + 4*j]     = pk2(OA1[4*j],   OA1[4*j+1]);
            os[rbA + 16 + 4*j + 1] = pk2(OA1[4*j+2], OA1[4*j+3]);
            os[rbB + 4*j]          = pk2(OB0[4*j],   OB0[4*j+1]);
            os[rbB + 4*j + 1]      = pk2(OB0[4*j+2], OB0[4*j+3]);
            os[rbB + 16 + 4*j]     = pk2(OB1[4*j],   OB1[4*j+1]);
            os[rbB + 16 + 4*j + 1] = pk2(OB1[4*j+2], OB1[4*j+3]);
        }
    }
    __syncthreads();

    const int ql = tid & 63, ug = (tid >> 6) * 8;   // 8 u32 = 16 d per thread
    const float M = fmaxf(fmaxf(mS[0][ql], mS[1][ql]), fmaxf(mS[2][ql], mS[3][ql]));
    float acc[16] = {};
    float L = 0.f;
    #pragma unroll
    for (int w2 = 0; w2 < 4; ++w2) {
        const float sc = __builtin_amdgcn_exp2f(mS[w2][ql] - M);
        L += lS[w2][ql] * sc;
        u32x4 pa = *(u32x4*)&OSu[w2][ql * 34 + ug];
        u32x4 pb = *(u32x4*)&OSu[w2][ql * 34 + ug + 4];
        #pragma unroll
        for (int t = 0; t < 4; ++t) {
            acc[2*t]     += __builtin_bit_cast(float, pa[t] << 16) * sc;
            acc[2*t+1]   += __builtin_bit_cast(float, pa[t] & 0xffff0000u) * sc;
            acc[8+2*t]   += __builtin_bit_cast(float, pb[t] << 16) * sc;
            acc[8+2*t+1] += __builtin_bit_cast(float, pb[t] & 0xffff0000u) * sc;
        }
    }
    const float inv = 1.0f / L;
    uint4 ov0, ov1;
    ov0.x = pk2(acc[0]*inv,  acc[1]*inv);
    ov0.y = pk2(acc[2]*inv,  acc[3]*inv);
    ov0.z = pk2(acc[4]*inv,  acc[5]*inv);
    ov0.w = pk2(acc[6]*inv,  acc[7]*inv);
    ov1.x = pk2(acc[8]*inv,  acc[9]*inv);
    ov1.y = pk2(acc[10]*inv, acc[11]*inv);
    ov1.z = pk2(acc[12]*inv, acc[13]*inv);
    ov1.w = pk2(acc[14]*inv, acc[15]*inv);
    unsigned short* orow = ab + ((size_t)(b * T_) + q0 + ql) * HID_ + hh * 64 + ug * 2;
    *(uint4*)orow       = ov0;
    *(uint4*)(orow + 8) = ov1;
}

extern "C" void kernel_launch(void* const* d_in, const int* in_sizes, int n_in,
                              void* d_out, int out_size, void* d_ws, size_t ws_size,
                              hipStream_t stream) {
    const float* x  = (const float*)d_in[0];
    const float* Wq = (const float*)d_in[1];
    const float* Wk = (const float*)d_in[2];
    const float* Wv = (const float*)d_in[3];
    const float* Wo = (const float*)d_in[4];
    const float* cs = (const float*)d_in[5];
    const float* sn = (const float*)d_in[6];
    char* wsb = (char*)d_ws;
    unsigned short* xb  = (unsigned short*)(wsb);                  // 8 MB
    unsigned short* wqb = (unsigned short*)(wsb + (8u  << 20));    // 2 MB each
    unsigned short* wkb = (unsigned short*)(wsb + (10u << 20));
    unsigned short* wvb = (unsigned short*)(wsb + (12u << 20));
    unsigned short* wob = (unsigned short*)(wsb + (14u << 20));
    unsigned short* qb  = (unsigned short*)(wsb + (16u << 20));
    unsigned short* kb  = (unsigned short*)(wsb + (24u << 20));
    unsigned short* vtb = (unsigned short*)(wsb + (32u << 20));
    unsigned short* ab  = (unsigned short*)(wsb + (40u << 20));

    cast_all<<<4096, 256, 0, stream>>>(x, Wq, Wk, Wv, Wo, xb, wqb, wkb, wvb, wob);

    gemm_k<0><<<768, 256, 0, stream>>>(
        xb, wqb, wkb, wvb, cs, sn, qb, kb, vtb, nullptr);
    attn16<<<1024, 256, 0, stream>>>(qb, kb, vtb, ab);
    gemm_k<1><<<512, 256, 0, stream>>>(
        ab, wob, nullptr, nullptr, nullptr, nullptr,
        nullptr, nullptr, nullptr, (float*)d_out);
}

// Round 23
// 113.904 us; speedup vs baseline: 1.2527x; 1.0246x over previous
//
#include <hip/hip_runtime.h>
#include <hip/hip_bf16.h>

#define B_   2
#define T_   2048
#define HID_ 1024
#define NH_  16
#define HD_  64
#define K_   1024
#define M_   (B_*T_)

typedef __attribute__((ext_vector_type(8)))  short bf16x8;
typedef __attribute__((ext_vector_type(4)))  float f32x4;
typedef __attribute__((ext_vector_type(16))) float f32x16;
typedef __attribute__((ext_vector_type(4)))  unsigned int u32x4;
typedef __attribute__((ext_vector_type(2)))  unsigned int u32x2;

#define LOG2E 1.44269504088896340736f

__device__ inline unsigned short f2bf(float f) {
    __hip_bfloat16 h = __float2bfloat16(f);
    return __builtin_bit_cast(unsigned short, h);
}
__device__ inline unsigned int pk2(float a, float b) {
    return (unsigned int)f2bf(a) | ((unsigned int)f2bf(b) << 16);
}
// truncation pack: (a>>16) | (b & 0xffff0000) in ONE v_perm_b32
__device__ inline unsigned int pkt(float a, float b) {
    return __builtin_amdgcn_perm(__builtin_bit_cast(unsigned, a),
                                 __builtin_bit_cast(unsigned, b), 0x03020706u);
}
__device__ inline bf16x8 cvt8(float4 a, float4 b) {
    bf16x8 r;
    r[0]=(short)f2bf(a.x); r[1]=(short)f2bf(a.y); r[2]=(short)f2bf(a.z); r[3]=(short)f2bf(a.w);
    r[4]=(short)f2bf(b.x); r[5]=(short)f2bf(b.y); r[6]=(short)f2bf(b.z); r[7]=(short)f2bf(b.w);
    return r;
}

// ---------------- fp32 -> bf16 cast, single launch (x + 4 weights) ----------------
__global__ __launch_bounds__(256)
void cast_all(const float* __restrict__ x,
              const float* __restrict__ W0, const float* __restrict__ W1,
              const float* __restrict__ W2, const float* __restrict__ W3,
              unsigned short* __restrict__ xo,
              unsigned short* __restrict__ o0, unsigned short* __restrict__ o1,
              unsigned short* __restrict__ o2, unsigned short* __restrict__ o3) {
    const int blk = blockIdx.x;
    const float* in;
    unsigned short* out;
    int i;
    if (blk < 2048) {
        in = x; out = xo; i = blk * 256 + threadIdx.x;
    } else {
        const int wb = blk - 2048, sec = wb >> 9;
        in  = (sec == 0) ? W0 : (sec == 1) ? W1 : (sec == 2) ? W2 : W3;
        out = (sec == 0) ? o0 : (sec == 1) ? o1 : (sec == 2) ? o2 : o3;
        i = (wb & 511) * 256 + threadIdx.x;
    }
    float4 a = ((const float4*)in)[2*i], b = ((const float4*)in)[2*i + 1];
    ((bf16x8*)out)[i] = cvt8(a, b);
}

// ---------------- bf16 GEMM-NT: reg-staged + XOR-swizzled LDS (proven) ----------------
template<int TYPE>
__global__ __launch_bounds__(256)
void gemm_k(const unsigned short* __restrict__ A, const unsigned short* __restrict__ W0,
            const unsigned short* __restrict__ W1, const unsigned short* __restrict__ W2,
            const float* __restrict__ cs, const float* __restrict__ sn,
            unsigned short* __restrict__ qb, unsigned short* __restrict__ kb,
            unsigned short* __restrict__ vtb, float* __restrict__ fout) {
    constexpr int BN = (TYPE == 1) ? 64 : 128;
    constexpr int NB = BN / 32;
    constexpr int NF = BN / 32;
    __shared__ unsigned short As[128*64];
    __shared__ unsigned short Bs[BN*64];
    const int tid = threadIdx.x;
    const int w = tid >> 6, lane = tid & 63;
    const int u = lane >> 4, c = lane & 15;
    const int bid = blockIdx.x;
    const int xcd = bid & 7, idx = bid >> 3;
    int bmi, bni;
    if constexpr (TYPE == 0) {
        bmi = (xcd & 3) * 8 + (idx & 7);
        bni = (xcd >> 2) * 12 + (idx >> 3);
    } else {
        bmi = (xcd & 3) * 8 + (idx & 7);
        bni = (xcd >> 2) * 8 + (idx >> 3);
    }
    const int bm = bmi * 128, bn = bni * BN;
    const int wm = (w & 1) * 64, wn = (w >> 1) * (BN / 2);
    const int srow = tid >> 3, scol = (tid & 7) << 3;

    const unsigned short* Wsec;
    int wrowbase;
    if constexpr (TYPE == 0) {
        const int sec = bn >> 10;
        Wsec = (sec == 0) ? W0 : ((sec == 1) ? W1 : W2);
        wrowbase = bn & 1023;
    } else {
        Wsec = W0;
        wrowbase = bn;
    }
    const unsigned short* Wp = Wsec + (size_t)(wrowbase + srow) * K_ + scol;
    const unsigned short* Ap = A + (size_t)(bm + srow) * K_ + scol;

    f32x4 acc[4][NF] = {};
    bf16x8 ra[4], rb[NB];

    auto loadin = [&](int k0) {
        #pragma unroll
        for (int i = 0; i < 4; ++i)
            ra[i] = *(const bf16x8*)(Ap + (size_t)i * 32 * K_ + k0);
        #pragma unroll
        for (int i = 0; i < NB; ++i)
            rb[i] = *(const bf16x8*)(Wp + (size_t)i * 32 * K_ + k0);
    };
    loadin(0);

    for (int k0 = 0; k0 < K_; k0 += 64) {
        __syncthreads();
        #pragma unroll
        for (int i = 0; i < 4; ++i) {
            const int row = i * 32 + srow;
            const int sc = (scol * 2) ^ ((row & 7) << 4);
            *(bf16x8*)((char*)As + row * 128 + sc) = ra[i];
        }
        #pragma unroll
        for (int i = 0; i < NB; ++i) {
            const int row = i * 32 + srow;
            const int sc = (scol * 2) ^ ((row & 7) << 4);
            *(bf16x8*)((char*)Bs + row * 128 + sc) = rb[i];
        }
        __syncthreads();
        if (k0 < K_ - 64) loadin(k0 + 64);
        #pragma unroll
        for (int kk = 0; kk < 2; ++kk) {
            bf16x8 af[4], bfr[NF];
            #pragma unroll
            for (int mi = 0; mi < 4; ++mi) {
                const int row = wm + mi * 16 + c;
                const int sc = (kk * 64 + u * 16) ^ ((row & 7) << 4);
                af[mi] = *(const bf16x8*)((char*)As + row * 128 + sc);
            }
            #pragma unroll
            for (int ni = 0; ni < NF; ++ni) {
                const int row = wn + ni * 16 + c;
                const int sc = (kk * 64 + u * 16) ^ ((row & 7) << 4);
                bfr[ni] = *(const bf16x8*)((char*)Bs + row * 128 + sc);
            }
            #pragma unroll
            for (int mi = 0; mi < 4; ++mi)
                #pragma unroll
                for (int ni = 0; ni < NF; ++ni)
                    acc[mi][ni] = __builtin_amdgcn_mfma_f32_16x16x32_bf16(
                        af[mi], bfr[ni], acc[mi][ni], 0, 0, 0);
        }
    }

    if constexpr (TYPE == 1) {
        #pragma unroll
        for (int mi = 0; mi < 4; ++mi)
            #pragma unroll
            for (int ni = 0; ni < NF; ++ni)
                #pragma unroll
                for (int r = 0; r < 4; ++r)
                    fout[(size_t)(bm + wm + 16*mi + 4*u + r) * HID_ + (bn + wn + 16*ni + c)] =
                        acc[mi][ni][r];
    } else {
        const int sec = bn >> 10;
        const int h = ((bn + wn) & 1023) >> 6;
        if (sec == 2) {
            #pragma unroll
            for (int mi = 0; mi < 4; ++mi)
                #pragma unroll
                for (int r = 0; r < 4; ++r) {
                    const int mg = bm + wm + 16*mi + 4*u + r;
                    const int bb = mg >> 11, t = mg & 2047;
                    const int tk = (t & ~12) | ((t & 4) << 1) | ((t & 8) >> 1);  // kappa
                    #pragma unroll
                    for (int ni = 0; ni < 4; ++ni)
                        vtb[((size_t)(bb*16 + h) * 64 + 16*ni + c) * 2048 + tk] =
                            f2bf(acc[mi][ni][r]);
                }
        } else {
            unsigned short* ob = sec ? kb : qb;
            const float qsc = sec ? 1.0f : (0.125f * LOG2E);   // q in log2 domain
            #pragma unroll
            for (int mi = 0; mi < 4; ++mi)
                #pragma unroll
                for (int r = 0; r < 4; ++r) {
                    const int mg = bm + wm + 16*mi + 4*u + r;
                    const int bb = mg >> 11, t = mg & 2047;
                    const size_t base = ((size_t)(bb*16 + h) * 2048 + t) * 64;
                    #pragma unroll
                    for (int ni = 0; ni < 2; ++ni) {
                        const int dlo = 16*ni + c;
                        const float cv = cs[t*64 + dlo], sv = sn[t*64 + dlo];
                        const float Aa = acc[mi][ni][r], Bb = acc[mi][ni+2][r];
                        ob[base + dlo]      = f2bf((Aa*cv - Bb*sv) * qsc);
                        ob[base + dlo + 32] = f2bf((Bb*cv + Aa*sv) * qsc);
                    }
                }
        }
    }
}

// ---------------- attn17: 96 q rows per wave (3 q-tiles), shared K/V ----------------
// Per-subtile fixed cost (K/V loads, loop, votes) amortized over 3 q-tiles:
// loads per bh drop 1056 -> 757 (-28%). Tiles processed SEQUENTIALLY (one p[16]
// live at a time) to cap VGPR (~210 < 256, no spill; 2 waves/SIMD unchanged).
// Tail chunk 21 (rows 2016-2047) = tile A only (uniform hasBC). Grid 704.
__global__ __launch_bounds__(256)
void attn17(const unsigned short* __restrict__ q, const unsigned short* __restrict__ k,
            const unsigned short* __restrict__ vt, unsigned short* __restrict__ ab) {
    const int raw = blockIdx.x;                          // 704 = 32 bh x 22 chunks
    const int bh     = (raw & 7) + 8 * ((raw >> 3) & 3); // same-bh -> same XCD
    const int qchunk = 21 - (raw >> 5);                  // heavy blocks first
    const bool hasBC = (qchunk < 21);
    const int tid = threadIdx.x;
    const int wid = tid >> 6, lane = tid & 63;
    const int h = lane >> 5, c = lane & 31;
    const int b = bh >> 4, hh = bh & 15;
    const int q0 = qchunk * 96;
    const int qgcA = q0 + c, qgcB = q0 + 32 + c, qgcC = q0 + 64 + c;
    const int stAd = 3 * qchunk;                         // tile diag subtiles
    const int stBd = stAd + 1, stCd = stAd + 2;
    const int NT   = hasBC ? (stAd + 3) : (stAd + 1);
    const unsigned short* qp = q  + (size_t)bh * (T_*64);
    const unsigned short* kp = k  + (size_t)bh * (T_*64);
    const unsigned short* vp = vt + (size_t)bh * (64*T_);

    const int kloff  = c * 64 + 8 * h;
    const int vloff0 = c * 2048 + 8 * h;
    const int vloff1 = vloff0 + 32 * 2048;

    bf16x8 qfA[4], qfB[4], qfC[4];
    {
        const unsigned short* qrowA = qp + (q0 + c) * 64 + 8 * h;
        #pragma unroll
        for (int s = 0; s < 4; ++s) qfA[s] = *(const bf16x8*)(qrowA + s * 16);
        if (hasBC) {
            #pragma unroll
            for (int s = 0; s < 4; ++s) {
                qfB[s] = *(const bf16x8*)(qrowA + 32 * 64 + s * 16);
                qfC[s] = *(const bf16x8*)(qrowA + 64 * 64 + s * 16);
            }
        }
    }

    f32x16 OA0 = {}, OA1 = {}, OB0 = {}, OB1 = {}, OC0 = {}, OC1 = {};
    float mA = -1e30f, lA = 0.f, mB = -1e30f, lB = 0.f, mC = -1e30f, lC = 0.f;

    auto loadK = [&](bf16x8 (&kf)[4], int st) {
        const unsigned short* kst = kp + (st << 11);
        #pragma unroll
        for (int s = 0; s < 4; ++s)
            kf[s] = *(const bf16x8*)(kst + kloff + s * 16);
    };

    // full per-tile pass: softmax (per-tile defer-vote) + PV
    auto tileRest = [&](f32x16 sa, int st, int std_, int qgc,
                        float& m, float& l, f32x16& O0, f32x16& O1,
                        const bf16x8& vf0, const bf16x8& vf1,
                        const bf16x8& vf2, const bf16x8& vf3) {
        const int kvs = st << 5;
        float p[16];
        #pragma unroll
        for (int r = 0; r < 16; ++r) p[r] = sa[r];
        if (st == std_) {                        // diagonal subtile only
            #pragma unroll
            for (int r = 0; r < 16; ++r) {
                const int kk = kvs + (r & 3) + 8 * (r >> 2) + 4 * h;
                if (kk > qgc) p[r] = -1e30f;
            }
        }
        const float a0 = fmaxf(fmaxf(p[0],  p[1]),  p[2]);
        const float a1 = fmaxf(fmaxf(p[3],  p[4]),  p[5]);
        const float a2 = fmaxf(fmaxf(p[6],  p[7]),  p[8]);
        const float a3 = fmaxf(fmaxf(p[9],  p[10]), p[11]);
        const float a4 = fmaxf(fmaxf(p[12], p[13]), p[14]);
        float mx = fmaxf(fmaxf(fmaxf(a0, a1), fmaxf(a2, a3)), fmaxf(a4, p[15]));
        if (!__all(mx <= m + 8.0f)) {            // defer-max (log2 domain)
            mx = fmaxf(mx, __shfl_xor(mx, 32));
            const float mn = fmaxf(m, mx);
            const float f = __builtin_amdgcn_exp2f(m - mn);
            m = mn; l *= f;
            #pragma unroll
            for (int r = 0; r < 16; ++r) { O0[r] *= f; O1[r] *= f; }
        }
        float ps = 0.f;
        #pragma unroll
        for (int r = 0; r < 16; ++r) {
            p[r] = __builtin_amdgcn_exp2f(p[r] - m);
            ps += p[r];
        }
        l += ps;
        u32x4 B0w = { pkt(p[0],  p[1]),  pkt(p[2],  p[3]),
                      pkt(p[4],  p[5]),  pkt(p[6],  p[7])  };
        u32x4 B1w = { pkt(p[8],  p[9]),  pkt(p[10], p[11]),
                      pkt(p[12], p[13]), pkt(p[14], p[15]) };
        bf16x8 PB0 = __builtin_bit_cast(bf16x8, B0w);
        bf16x8 PB1 = __builtin_bit_cast(bf16x8, B1w);
        __builtin_amdgcn_s_setprio(1);
        O0 = __builtin_amdgcn_mfma_f32_32x32x16_bf16(vf0, PB0, O0, 0, 0, 0);
        O0 = __builtin_amdgcn_mfma_f32_32x32x16_bf16(vf1, PB1, O0, 0, 0, 0);
        O1 = __builtin_amdgcn_mfma_f32_32x32x16_bf16(vf2, PB0, O1, 0, 0, 0);
        O1 = __builtin_amdgcn_mfma_f32_32x32x16_bf16(vf3, PB1, O1, 0, 0, 0);
        __builtin_amdgcn_s_setprio(0);
    };

    auto qkt = [&](const bf16x8 (&kf)[4], const bf16x8 (&qf)[4]) -> f32x16 {
        __builtin_amdgcn_s_setprio(1);
        f32x16 sa = {};
        #pragma unroll
        for (int s = 0; s < 4; ++s)
            sa = __builtin_amdgcn_mfma_f32_32x32x16_bf16(kf[s], qf[s], sa, 0, 0, 0);
        __builtin_amdgcn_s_setprio(0);
        return sa;
    };

    bf16x8 kf_[4];
    if (wid < NT) {
        loadK(kf_, wid);
        for (int st = wid; st < NT; st += 4) {
            // V loads issue first; consumed after QK^T+softmax of tile A
            const unsigned short* vst = vp + (st << 5);
            bf16x8 vf0 = *(const bf16x8*)(vst + vloff0);
            bf16x8 vf1 = *(const bf16x8*)(vst + vloff0 + 16);
            bf16x8 vf2 = *(const bf16x8*)(vst + vloff1);
            bf16x8 vf3 = *(const bf16x8*)(vst + vloff1 + 16);
            const bool doA = (st <= stAd);
            const bool doB = hasBC && (st <= stBd);
            if (doA) {
                f32x16 sa = qkt(kf_, qfA);
                if (!hasBC && st + 4 < NT) loadK(kf_, st + 4);   // A is last kf read
                tileRest(sa, st, stAd, qgcA, mA, lA, OA0, OA1, vf0, vf1, vf2, vf3);
            }
            if (doB) {
                f32x16 sa = qkt(kf_, qfB);
                tileRest(sa, st, stBd, qgcB, mB, lB, OB0, OB1, vf0, vf1, vf2, vf3);
            }
            if (hasBC) {
                f32x16 sa = qkt(kf_, qfC);
                if (st + 4 < NT) loadK(kf_, st + 4);             // C is last kf read
                tileRest(sa, st, stCd, qgcC, mC, lC, OC0, OC1, vf0, vf1, vf2, vf3);
            }
        }
    }
    lA += __shfl_xor(lA, 32);
    lB += __shfl_xor(lB, 32);
    lC += __shfl_xor(lC, 32);

    // ---- merge the 4 wave-partials in LDS (bf16-packed, stride 34 u32) ----
    __shared__ unsigned OSu[4][96 * 34];
    __shared__ float mS[4][96], lS[4][96];
    if (h == 0) {
        mS[wid][c] = mA;      lS[wid][c] = lA;
        mS[wid][32 + c] = mB; lS[wid][32 + c] = lB;
        mS[wid][64 + c] = mC; lS[wid][64 + c] = lC;
    }
    {
        unsigned* os = &OSu[wid][0];
        const int rbA = c * 34 + 2 * h;
        const int rbB = (32 + c) * 34 + 2 * h;
        const int rbC = (64 + c) * 34 + 2 * h;
        #pragma unroll
        for (int j = 0; j < 4; ++j) {
            os[rbA + 4*j]          = pk2(OA0[4*j],   OA0[4*j+1]);
            os[rbA + 4*j + 1]      = pk2(OA0[4*j+2], OA0[4*j+3]);
            os[rbA + 16 + 4*j]     = pk2(OA1[4*j],   OA1[4*j+1]);
            os[rbA + 16 + 4*j + 1] = pk2(OA1[4*j+2], OA1[4*j+3]);
            os[rbB + 4*j]          = pk2(OB0[4*j],   OB0[4*j+1]);
            os[rbB + 4*j + 1]      = pk2(OB0[4*j+2], OB0[4*j+3]);
            os[rbB + 16 + 4*j]     = pk2(OB1[4*j],   OB1[4*j+1]);
            os[rbB + 16 + 4*j + 1] = pk2(OB1[4*j+2], OB1[4*j+3]);
            os[rbC + 4*j]          = pk2(OC0[4*j],   OC0[4*j+1]);
            os[rbC + 4*j + 1]      = pk2(OC0[4*j+2], OC0[4*j+3]);
            os[rbC + 16 + 4*j]     = pk2(OC1[4*j],   OC1[4*j+1]);
            os[rbC + 16 + 4*j + 1] = pk2(OC1[4*j+2], OC1[4*j+3]);
        }
    }
    __syncthreads();

    // 3 passes of 32 rows; each thread handles 4 u32 = 8 d
    #pragma unroll
    for (int rr = 0; rr < 3; ++rr) {
        if (rr > 0 && !hasBC) break;
        const int rl = rr * 32 + (tid & 31);
        const int ug = (tid >> 5) * 4;               // 0,4,...,28
        const float M = fmaxf(fmaxf(mS[0][rl], mS[1][rl]), fmaxf(mS[2][rl], mS[3][rl]));
        float acc[8] = {};
        float L = 0.f;
        #pragma unroll
        for (int w2 = 0; w2 < 4; ++w2) {
            const float sc = __builtin_amdgcn_exp2f(mS[w2][rl] - M);
            L += lS[w2][rl] * sc;
            u32x4 pa = *(u32x4*)&OSu[w2][rl * 34 + ug];
            #pragma unroll
            for (int t = 0; t < 4; ++t) {
                acc[2*t]   += __builtin_bit_cast(float, pa[t] << 16) * sc;
                acc[2*t+1] += __builtin_bit_cast(float, pa[t] & 0xffff0000u) * sc;
            }
        }
        const float inv = 1.0f / L;
        uint4 ov;
        ov.x = pk2(acc[0]*inv, acc[1]*inv);
        ov.y = pk2(acc[2]*inv, acc[3]*inv);
        ov.z = pk2(acc[4]*inv, acc[5]*inv);
        ov.w = pk2(acc[6]*inv, acc[7]*inv);
        *(uint4*)(ab + ((size_t)(b * T_) + q0 + rl) * HID_ + hh * 64 + ug * 2) = ov;
    }
}

extern "C" void kernel_launch(void* const* d_in, const int* in_sizes, int n_in,
                              void* d_out, int out_size, void* d_ws, size_t ws_size,
                              hipStream_t stream) {
    const float* x  = (const float*)d_in[0];
    const float* Wq = (const float*)d_in[1];
    const float* Wk = (const float*)d_in[2];
    const float* Wv = (const float*)d_in[3];
    const float* Wo = (const float*)d_in[4];
    const float* cs = (const float*)d_in[5];
    const float* sn = (const float*)d_in[6];
    char* wsb = (char*)d_ws;
    unsigned short* xb  = (unsigned short*)(wsb);                  // 8 MB
    unsigned short* wqb = (unsigned short*)(wsb + (8u  << 20));    // 2 MB each
    unsigned short* wkb = (unsigned short*)(wsb + (10u << 20));
    unsigned short* wvb = (unsigned short*)(wsb + (12u << 20));
    unsigned short* wob = (unsigned short*)(wsb + (14u << 20));
    unsigned short* qb  = (unsigned short*)(wsb + (16u << 20));
    unsigned short* kb  = (unsigned short*)(wsb + (24u << 20));
    unsigned short* vtb = (unsigned short*)(wsb + (32u << 20));
    unsigned short* ab  = (unsigned short*)(wsb + (40u << 20));

    cast_all<<<4096, 256, 0, stream>>>(x, Wq, Wk, Wv, Wo, xb, wqb, wkb, wvb, wob);

    gemm_k<0><<<768, 256, 0, stream>>>(
        xb, wqb, wkb, wvb, cs, sn, qb, kb, vtb, nullptr);
    attn17<<<704, 256, 0, stream>>>(qb, kb, vtb, ab);
    gemm_k<1><<<512, 256, 0, stream>>>(
        ab, wob, nullptr, nullptr, nullptr, nullptr,
        nullptr, nullptr, nullptr, (float*)d_out);
}

// Round 24
// 108.134 us; speedup vs baseline: 1.3196x; 1.0534x over previous
//
#include <hip/hip_runtime.h>
#include <hip/hip_bf16.h>

#define B_   2
#define T_   2048
#define HID_ 1024
#define NH_  16
#define HD_  64
#define K_   1024
#define M_   (B_*T_)

typedef __attribute__((ext_vector_type(8)))  short bf16x8;
typedef __attribute__((ext_vector_type(4)))  float f32x4;
typedef __attribute__((ext_vector_type(16))) float f32x16;
typedef __attribute__((ext_vector_type(4)))  unsigned int u32x4;
typedef __attribute__((ext_vector_type(2)))  unsigned int u32x2;

#define LOG2E 1.44269504088896340736f

__device__ inline unsigned short f2bf(float f) {
    __hip_bfloat16 h = __float2bfloat16(f);
    return __builtin_bit_cast(unsigned short, h);
}
__device__ inline unsigned int pk2(float a, float b) {
    return (unsigned int)f2bf(a) | ((unsigned int)f2bf(b) << 16);
}
// truncation pack: (a>>16) | (b & 0xffff0000) in ONE v_perm_b32
__device__ inline unsigned int pkt(float a, float b) {
    return __builtin_amdgcn_perm(__builtin_bit_cast(unsigned, a),
                                 __builtin_bit_cast(unsigned, b), 0x03020706u);
}
__device__ inline bf16x8 cvt8(float4 a, float4 b) {
    bf16x8 r;
    r[0]=(short)f2bf(a.x); r[1]=(short)f2bf(a.y); r[2]=(short)f2bf(a.z); r[3]=(short)f2bf(a.w);
    r[4]=(short)f2bf(b.x); r[5]=(short)f2bf(b.y); r[6]=(short)f2bf(b.z); r[7]=(short)f2bf(b.w);
    return r;
}

// ---------------- fp32 -> bf16 cast, single launch (x + 4 weights) ----------------
__global__ __launch_bounds__(256)
void cast_all(const float* __restrict__ x,
              const float* __restrict__ W0, const float* __restrict__ W1,
              const float* __restrict__ W2, const float* __restrict__ W3,
              unsigned short* __restrict__ xo,
              unsigned short* __restrict__ o0, unsigned short* __restrict__ o1,
              unsigned short* __restrict__ o2, unsigned short* __restrict__ o3) {
    const int blk = blockIdx.x;
    const float* in;
    unsigned short* out;
    int i;
    if (blk < 2048) {
        in = x; out = xo; i = blk * 256 + threadIdx.x;
    } else {
        const int wb = blk - 2048, sec = wb >> 9;
        in  = (sec == 0) ? W0 : (sec == 1) ? W1 : (sec == 2) ? W2 : W3;
        out = (sec == 0) ? o0 : (sec == 1) ? o1 : (sec == 2) ? o2 : o3;
        i = (wb & 511) * 256 + threadIdx.x;
    }
    float4 a = ((const float4*)in)[2*i], b = ((const float4*)in)[2*i + 1];
    ((bf16x8*)out)[i] = cvt8(a, b);
}

// ---------------- bf16 GEMM-NT: reg-staged + XOR-swizzled LDS (proven) ----------------
template<int TYPE>
__global__ __launch_bounds__(256)
void gemm_k(const unsigned short* __restrict__ A, const unsigned short* __restrict__ W0,
            const unsigned short* __restrict__ W1, const unsigned short* __restrict__ W2,
            const float* __restrict__ cs, const float* __restrict__ sn,
            unsigned short* __restrict__ qb, unsigned short* __restrict__ kb,
            unsigned short* __restrict__ vtb, float* __restrict__ fout) {
    constexpr int BN = (TYPE == 1) ? 64 : 128;
    constexpr int NB = BN / 32;
    constexpr int NF = BN / 32;
    __shared__ unsigned short As[128*64];
    __shared__ unsigned short Bs[BN*64];
    const int tid = threadIdx.x;
    const int w = tid >> 6, lane = tid & 63;
    const int u = lane >> 4, c = lane & 15;
    const int bid = blockIdx.x;
    const int xcd = bid & 7, idx = bid >> 3;
    int bmi, bni;
    if constexpr (TYPE == 0) {
        bmi = (xcd & 3) * 8 + (idx & 7);
        bni = (xcd >> 2) * 12 + (idx >> 3);
    } else {
        bmi = (xcd & 3) * 8 + (idx & 7);
        bni = (xcd >> 2) * 8 + (idx >> 3);
    }
    const int bm = bmi * 128, bn = bni * BN;
    const int wm = (w & 1) * 64, wn = (w >> 1) * (BN / 2);
    const int srow = tid >> 3, scol = (tid & 7) << 3;

    const unsigned short* Wsec;
    int wrowbase;
    if constexpr (TYPE == 0) {
        const int sec = bn >> 10;
        Wsec = (sec == 0) ? W0 : ((sec == 1) ? W1 : W2);
        wrowbase = bn & 1023;
    } else {
        Wsec = W0;
        wrowbase = bn;
    }
    const unsigned short* Wp = Wsec + (size_t)(wrowbase + srow) * K_ + scol;
    const unsigned short* Ap = A + (size_t)(bm + srow) * K_ + scol;

    f32x4 acc[4][NF] = {};
    bf16x8 ra[4], rb[NB];

    auto loadin = [&](int k0) {
        #pragma unroll
        for (int i = 0; i < 4; ++i)
            ra[i] = *(const bf16x8*)(Ap + (size_t)i * 32 * K_ + k0);
        #pragma unroll
        for (int i = 0; i < NB; ++i)
            rb[i] = *(const bf16x8*)(Wp + (size_t)i * 32 * K_ + k0);
    };
    loadin(0);

    for (int k0 = 0; k0 < K_; k0 += 64) {
        __syncthreads();
        #pragma unroll
        for (int i = 0; i < 4; ++i) {
            const int row = i * 32 + srow;
            const int sc = (scol * 2) ^ ((row & 7) << 4);
            *(bf16x8*)((char*)As + row * 128 + sc) = ra[i];
        }
        #pragma unroll
        for (int i = 0; i < NB; ++i) {
            const int row = i * 32 + srow;
            const int sc = (scol * 2) ^ ((row & 7) << 4);
            *(bf16x8*)((char*)Bs + row * 128 + sc) = rb[i];
        }
        __syncthreads();
        if (k0 < K_ - 64) loadin(k0 + 64);
        #pragma unroll
        for (int kk = 0; kk < 2; ++kk) {
            bf16x8 af[4], bfr[NF];
            #pragma unroll
            for (int mi = 0; mi < 4; ++mi) {
                const int row = wm + mi * 16 + c;
                const int sc = (kk * 64 + u * 16) ^ ((row & 7) << 4);
                af[mi] = *(const bf16x8*)((char*)As + row * 128 + sc);
            }
            #pragma unroll
            for (int ni = 0; ni < NF; ++ni) {
                const int row = wn + ni * 16 + c;
                const int sc = (kk * 64 + u * 16) ^ ((row & 7) << 4);
                bfr[ni] = *(const bf16x8*)((char*)Bs + row * 128 + sc);
            }
            #pragma unroll
            for (int mi = 0; mi < 4; ++mi)
                #pragma unroll
                for (int ni = 0; ni < NF; ++ni)
                    acc[mi][ni] = __builtin_amdgcn_mfma_f32_16x16x32_bf16(
                        af[mi], bfr[ni], acc[mi][ni], 0, 0, 0);
        }
    }

    if constexpr (TYPE == 1) {
        #pragma unroll
        for (int mi = 0; mi < 4; ++mi)
            #pragma unroll
            for (int ni = 0; ni < NF; ++ni)
                #pragma unroll
                for (int r = 0; r < 4; ++r)
                    fout[(size_t)(bm + wm + 16*mi + 4*u + r) * HID_ + (bn + wn + 16*ni + c)] =
                        acc[mi][ni][r];
    } else {
        const int sec = bn >> 10;
        const int h = ((bn + wn) & 1023) >> 6;
        if (sec == 2) {
            #pragma unroll
            for (int mi = 0; mi < 4; ++mi)
                #pragma unroll
                for (int r = 0; r < 4; ++r) {
                    const int mg = bm + wm + 16*mi + 4*u + r;
                    const int bb = mg >> 11, t = mg & 2047;
                    const int tk = (t & ~12) | ((t & 4) << 1) | ((t & 8) >> 1);  // kappa
                    #pragma unroll
                    for (int ni = 0; ni < 4; ++ni)
                        vtb[((size_t)(bb*16 + h) * 64 + 16*ni + c) * 2048 + tk] =
                            f2bf(acc[mi][ni][r]);
                }
        } else {
            unsigned short* ob = sec ? kb : qb;
            const float qsc = sec ? 1.0f : (0.125f * LOG2E);   // q in log2 domain
            #pragma unroll
            for (int mi = 0; mi < 4; ++mi)
                #pragma unroll
                for (int r = 0; r < 4; ++r) {
                    const int mg = bm + wm + 16*mi + 4*u + r;
                    const int bb = mg >> 11, t = mg & 2047;
                    const size_t base = ((size_t)(bb*16 + h) * 2048 + t) * 64;
                    #pragma unroll
                    for (int ni = 0; ni < 2; ++ni) {
                        const int dlo = 16*ni + c;
                        const float cv = cs[t*64 + dlo], sv = sn[t*64 + dlo];
                        const float Aa = acc[mi][ni][r], Bb = acc[mi][ni+2][r];
                        ob[base + dlo]      = f2bf((Aa*cv - Bb*sv) * qsc);
                        ob[base + dlo + 32] = f2bf((Bb*cv + Aa*sv) * qsc);
                    }
                }
        }
    }
}

// ---------------- attn18: 128 q rows per wave (4 q-tiles), shared K/V ----------------
// Loads/votes per bh: 757 -> 544 (-28% vs 3-tile). T=2048=16x128: NO tail chunk.
// Tiles sequential (one p[16] live); est ~220 VGPR (<256 keeps 2 waves/SIMD).
// Grid 512 = 32 bh x 16 chunks, heavy-first, XCD swizzle.
__global__ __launch_bounds__(256)
void attn18(const unsigned short* __restrict__ q, const unsigned short* __restrict__ k,
            const unsigned short* __restrict__ vt, unsigned short* __restrict__ ab) {
    const int raw = blockIdx.x;                          // 512 = 32 bh x 16 chunks
    const int bh     = (raw & 7) + 8 * ((raw >> 3) & 3); // same-bh -> same XCD
    const int qchunk = 15 - (raw >> 5);                  // heavy blocks first
    const int tid = threadIdx.x;
    const int wid = tid >> 6, lane = tid & 63;
    const int h = lane >> 5, c = lane & 31;
    const int b = bh >> 4, hh = bh & 15;
    const int q0 = qchunk * 128;
    const int qgcA = q0 + c, qgcB = q0 + 32 + c, qgcC = q0 + 64 + c, qgcD = q0 + 96 + c;
    const int stAd = 4 * qchunk;                         // tile diag subtiles
    const int stBd = stAd + 1, stCd = stAd + 2, stDd = stAd + 3;
    const int NT   = stAd + 4;
    const unsigned short* qp = q  + (size_t)bh * (T_*64);
    const unsigned short* kp = k  + (size_t)bh * (T_*64);
    const unsigned short* vp = vt + (size_t)bh * (64*T_);

    const int kloff  = c * 64 + 8 * h;
    const int vloff0 = c * 2048 + 8 * h;
    const int vloff1 = vloff0 + 32 * 2048;

    bf16x8 qfA[4], qfB[4], qfC[4], qfD[4];
    {
        const unsigned short* qrowA = qp + (q0 + c) * 64 + 8 * h;
        #pragma unroll
        for (int s = 0; s < 4; ++s) {
            qfA[s] = *(const bf16x8*)(qrowA + s * 16);
            qfB[s] = *(const bf16x8*)(qrowA + 32 * 64 + s * 16);
            qfC[s] = *(const bf16x8*)(qrowA + 64 * 64 + s * 16);
            qfD[s] = *(const bf16x8*)(qrowA + 96 * 64 + s * 16);
        }
    }

    f32x16 OA0 = {}, OA1 = {}, OB0 = {}, OB1 = {};
    f32x16 OC0 = {}, OC1 = {}, OD0 = {}, OD1 = {};
    float mA = -1e30f, lA = 0.f, mB = -1e30f, lB = 0.f;
    float mC = -1e30f, lC = 0.f, mD = -1e30f, lD = 0.f;

    auto loadK = [&](bf16x8 (&kf)[4], int st) {
        const unsigned short* kst = kp + (st << 11);
        #pragma unroll
        for (int s = 0; s < 4; ++s)
            kf[s] = *(const bf16x8*)(kst + kloff + s * 16);
    };

    // full per-tile pass: causal mask + softmax (per-tile defer-vote) + PV
    auto tileRest = [&](f32x16 sa, int st, int std_, int qgc,
                        float& m, float& l, f32x16& O0, f32x16& O1,
                        const bf16x8& vf0, const bf16x8& vf1,
                        const bf16x8& vf2, const bf16x8& vf3) {
        const int kvs = st << 5;
        float p[16];
        #pragma unroll
        for (int r = 0; r < 16; ++r) p[r] = sa[r];
        if (st == std_) {                        // diagonal subtile only
            #pragma unroll
            for (int r = 0; r < 16; ++r) {
                const int kk = kvs + (r & 3) + 8 * (r >> 2) + 4 * h;
                if (kk > qgc) p[r] = -1e30f;
            }
        }
        const float a0 = fmaxf(fmaxf(p[0],  p[1]),  p[2]);
        const float a1 = fmaxf(fmaxf(p[3],  p[4]),  p[5]);
        const float a2 = fmaxf(fmaxf(p[6],  p[7]),  p[8]);
        const float a3 = fmaxf(fmaxf(p[9],  p[10]), p[11]);
        const float a4 = fmaxf(fmaxf(p[12], p[13]), p[14]);
        float mx = fmaxf(fmaxf(fmaxf(a0, a1), fmaxf(a2, a3)), fmaxf(a4, p[15]));
        if (!__all(mx <= m + 8.0f)) {            // defer-max (log2 domain)
            mx = fmaxf(mx, __shfl_xor(mx, 32));
            const float mn = fmaxf(m, mx);
            const float f = __builtin_amdgcn_exp2f(m - mn);
            m = mn; l *= f;
            #pragma unroll
            for (int r = 0; r < 16; ++r) { O0[r] *= f; O1[r] *= f; }
        }
        float ps = 0.f;
        #pragma unroll
        for (int r = 0; r < 16; ++r) {
            p[r] = __builtin_amdgcn_exp2f(p[r] - m);
            ps += p[r];
        }
        l += ps;
        u32x4 B0w = { pkt(p[0],  p[1]),  pkt(p[2],  p[3]),
                      pkt(p[4],  p[5]),  pkt(p[6],  p[7])  };
        u32x4 B1w = { pkt(p[8],  p[9]),  pkt(p[10], p[11]),
                      pkt(p[12], p[13]), pkt(p[14], p[15]) };
        bf16x8 PB0 = __builtin_bit_cast(bf16x8, B0w);
        bf16x8 PB1 = __builtin_bit_cast(bf16x8, B1w);
        __builtin_amdgcn_s_setprio(1);
        O0 = __builtin_amdgcn_mfma_f32_32x32x16_bf16(vf0, PB0, O0, 0, 0, 0);
        O0 = __builtin_amdgcn_mfma_f32_32x32x16_bf16(vf1, PB1, O0, 0, 0, 0);
        O1 = __builtin_amdgcn_mfma_f32_32x32x16_bf16(vf2, PB0, O1, 0, 0, 0);
        O1 = __builtin_amdgcn_mfma_f32_32x32x16_bf16(vf3, PB1, O1, 0, 0, 0);
        __builtin_amdgcn_s_setprio(0);
    };

    auto qkt = [&](const bf16x8 (&kf)[4], const bf16x8 (&qf)[4]) -> f32x16 {
        __builtin_amdgcn_s_setprio(1);
        f32x16 sa = {};
        #pragma unroll
        for (int s = 0; s < 4; ++s)
            sa = __builtin_amdgcn_mfma_f32_32x32x16_bf16(kf[s], qf[s], sa, 0, 0, 0);
        __builtin_amdgcn_s_setprio(0);
        return sa;
    };

    bf16x8 kf_[4];
    if (wid < NT) {
        loadK(kf_, wid);
        for (int st = wid; st < NT; st += 4) {
            // V loads issue first; consumed after QK^T+softmax of tile A
            const unsigned short* vst = vp + (st << 5);
            bf16x8 vf0 = *(const bf16x8*)(vst + vloff0);
            bf16x8 vf1 = *(const bf16x8*)(vst + vloff0 + 16);
            bf16x8 vf2 = *(const bf16x8*)(vst + vloff1);
            bf16x8 vf3 = *(const bf16x8*)(vst + vloff1 + 16);
            const bool doA = (st <= stAd);
            const bool doB = (st <= stBd);
            const bool doC = (st <= stCd);
            if (doA) {
                f32x16 sa = qkt(kf_, qfA);
                tileRest(sa, st, stAd, qgcA, mA, lA, OA0, OA1, vf0, vf1, vf2, vf3);
            }
            if (doB) {
                f32x16 sa = qkt(kf_, qfB);
                tileRest(sa, st, stBd, qgcB, mB, lB, OB0, OB1, vf0, vf1, vf2, vf3);
            }
            if (doC) {
                f32x16 sa = qkt(kf_, qfC);
                tileRest(sa, st, stCd, qgcC, mC, lC, OC0, OC1, vf0, vf1, vf2, vf3);
            }
            {
                f32x16 sa = qkt(kf_, qfD);
                if (st + 4 < NT) loadK(kf_, st + 4);     // D is last kf read
                tileRest(sa, st, stDd, qgcD, mD, lD, OD0, OD1, vf0, vf1, vf2, vf3);
            }
        }
    }
    lA += __shfl_xor(lA, 32);
    lB += __shfl_xor(lB, 32);
    lC += __shfl_xor(lC, 32);
    lD += __shfl_xor(lD, 32);

    // ---- merge the 4 wave-partials in LDS (bf16-packed, stride 34 u32) ----
    __shared__ unsigned OSu[4][128 * 34];
    __shared__ float mS[4][128], lS[4][128];
    if (h == 0) {
        mS[wid][c] = mA;      lS[wid][c] = lA;
        mS[wid][32 + c] = mB; lS[wid][32 + c] = lB;
        mS[wid][64 + c] = mC; lS[wid][64 + c] = lC;
        mS[wid][96 + c] = mD; lS[wid][96 + c] = lD;
    }
    {
        unsigned* os = &OSu[wid][0];
        const int rbA = c * 34 + 2 * h;
        const int rbB = (32 + c) * 34 + 2 * h;
        const int rbC = (64 + c) * 34 + 2 * h;
        const int rbD = (96 + c) * 34 + 2 * h;
        #pragma unroll
        for (int j = 0; j < 4; ++j) {
            os[rbA + 4*j]          = pk2(OA0[4*j],   OA0[4*j+1]);
            os[rbA + 4*j + 1]      = pk2(OA0[4*j+2], OA0[4*j+3]);
            os[rbA + 16 + 4*j]     = pk2(OA1[4*j],   OA1[4*j+1]);
            os[rbA + 16 + 4*j + 1] = pk2(OA1[4*j+2], OA1[4*j+3]);
            os[rbB + 4*j]          = pk2(OB0[4*j],   OB0[4*j+1]);
            os[rbB + 4*j + 1]      = pk2(OB0[4*j+2], OB0[4*j+3]);
            os[rbB + 16 + 4*j]     = pk2(OB1[4*j],   OB1[4*j+1]);
            os[rbB + 16 + 4*j + 1] = pk2(OB1[4*j+2], OB1[4*j+3]);
            os[rbC + 4*j]          = pk2(OC0[4*j],   OC0[4*j+1]);
            os[rbC + 4*j + 1]      = pk2(OC0[4*j+2], OC0[4*j+3]);
            os[rbC + 16 + 4*j]     = pk2(OC1[4*j],   OC1[4*j+1]);
            os[rbC + 16 + 4*j + 1] = pk2(OC1[4*j+2], OC1[4*j+3]);
            os[rbD + 4*j]          = pk2(OD0[4*j],   OD0[4*j+1]);
            os[rbD + 4*j + 1]      = pk2(OD0[4*j+2], OD0[4*j+3]);
            os[rbD + 16 + 4*j]     = pk2(OD1[4*j],   OD1[4*j+1]);
            os[rbD + 16 + 4*j + 1] = pk2(OD1[4*j+2], OD1[4*j+3]);
        }
    }
    __syncthreads();

    // 4 passes of 32 rows; each thread handles 4 u32 = 8 d
    #pragma unroll
    for (int rr = 0; rr < 4; ++rr) {
        const int rl = rr * 32 + (tid & 31);
        const int ug = (tid >> 5) * 4;               // 0,4,...,28
        const float M = fmaxf(fmaxf(mS[0][rl], mS[1][rl]), fmaxf(mS[2][rl], mS[3][rl]));
        float acc[8] = {};
        float L = 0.f;
        #pragma unroll
        for (int w2 = 0; w2 < 4; ++w2) {
            const float sc = __builtin_amdgcn_exp2f(mS[w2][rl] - M);
            L += lS[w2][rl] * sc;
            u32x4 pa = *(u32x4*)&OSu[w2][rl * 34 + ug];
            #pragma unroll
            for (int t = 0; t < 4; ++t) {
                acc[2*t]   += __builtin_bit_cast(float, pa[t] << 16) * sc;
                acc[2*t+1] += __builtin_bit_cast(float, pa[t] & 0xffff0000u) * sc;
            }
        }
        const float inv = 1.0f / L;
        uint4 ov;
        ov.x = pk2(acc[0]*inv, acc[1]*inv);
        ov.y = pk2(acc[2]*inv, acc[3]*inv);
        ov.z = pk2(acc[4]*inv, acc[5]*inv);
        ov.w = pk2(acc[6]*inv, acc[7]*inv);
        *(uint4*)(ab + ((size_t)(b * T_) + q0 + rl) * HID_ + hh * 64 + ug * 2) = ov;
    }
}

extern "C" void kernel_launch(void* const* d_in, const int* in_sizes, int n_in,
                              void* d_out, int out_size, void* d_ws, size_t ws_size,
                              hipStream_t stream) {
    const float* x  = (const float*)d_in[0];
    const float* Wq = (const float*)d_in[1];
    const float* Wk = (const float*)d_in[2];
    const float* Wv = (const float*)d_in[3];
    const float* Wo = (const float*)d_in[4];
    const float* cs = (const float*)d_in[5];
    const float* sn = (const float*)d_in[6];
    char* wsb = (char*)d_ws;
    unsigned short* xb  = (unsigned short*)(wsb);                  // 8 MB
    unsigned short* wqb = (unsigned short*)(wsb + (8u  << 20));    // 2 MB each
    unsigned short* wkb = (unsigned short*)(wsb + (10u << 20));
    unsigned short* wvb = (unsigned short*)(wsb + (12u << 20));
    unsigned short* wob = (unsigned short*)(wsb + (14u << 20));
    unsigned short* qb  = (unsigned short*)(wsb + (16u << 20));
    unsigned short* kb  = (unsigned short*)(wsb + (24u << 20));
    unsigned short* vtb = (unsigned short*)(wsb + (32u << 20));
    unsigned short* ab  = (unsigned short*)(wsb + (40u << 20));

    cast_all<<<4096, 256, 0, stream>>>(x, Wq, Wk, Wv, Wo, xb, wqb, wkb, wvb, wob);

    gemm_k<0><<<768, 256, 0, stream>>>(
        xb, wqb, wkb, wvb, cs, sn, qb, kb, vtb, nullptr);
    attn18<<<512, 256, 0, stream>>>(qb, kb, vtb, ab);
    gemm_k<1><<<512, 256, 0, stream>>>(
        ab, wob, nullptr, nullptr, nullptr, nullptr,
        nullptr, nullptr, nullptr, (float*)d_out);
}